// Round 1
// baseline (254.951 us; speedup 1.0000x reference)
//
#include <hip/hip_runtime.h>

#define S_LEN 2048
#define NH 16
#define DH 64
#define DM 1024
#define M_TOK 8192              // B*S
#define SZX ((size_t)M_TOK * DM)   // 8 Mi elems
#define SZW ((size_t)DM * DM)      // 1 Mi elems (2^20)
#define NT 16                   // DM/64 K-tiles

typedef unsigned short u16;
typedef unsigned int u32;
typedef __attribute__((ext_vector_type(8))) short bf16x8;   // 8 bf16 = 4 VGPRs
typedef __attribute__((ext_vector_type(4))) float f32x4;

// round-half-up bf16 (error bound == RNE except exact ties)
__device__ __forceinline__ u16 f2bf(float f) {
  union { float f; u32 u; } v; v.f = f;
  return (u16)((v.u + 0x8000u) >> 16);
}
// pack two floats -> (bf16(y)<<16)|bf16(x) in 2 adds + 1 v_perm
__device__ __forceinline__ u32 pack_bf2(float x, float y) {
  union { float f; u32 u; } a, b; a.f = x; b.f = y;
  return __builtin_amdgcn_perm(b.u + 0x8000u, a.u + 0x8000u, 0x07060302u);
}
__device__ __forceinline__ float fast_exp2(float x) {
  float r; asm("v_exp_f32 %0, %1" : "=v"(r) : "v"(x)); return r;
}
// async global->LDS, 16B/lane. dest = wave-uniform base + lane*16.
__device__ __forceinline__ void gload16(const u16* g, u16* l) {
  __builtin_amdgcn_global_load_lds((const __attribute__((address_space(1))) void*)g,
                                   (__attribute__((address_space(3))) void*)l,
                                   16, 0, 0);
}

#define QSCALE 0.18033688f   // 1/sqrt(64) * log2(e)

// Fused cast: X (8Mi) + Wq|Wk|Wv|Wo (4 x 1Mi) -> contiguous bf16 dst.
__global__ __launch_bounds__(256) void cast_all(const float* __restrict__ X,
                                                const float* __restrict__ q,
                                                const float* __restrict__ k,
                                                const float* __restrict__ v,
                                                const float* __restrict__ o,
                                                u16* __restrict__ dst) {
  const int i = (blockIdx.x * 256 + threadIdx.x) * 8;   // [0, 12Mi)
  const float* src;
  int local;
  if (i < (int)SZX) { src = X; local = i; }
  else {
    const int j = i - (int)SZX;
    const int region = j >> 20;
    src = (region == 0) ? q : (region == 1) ? k : (region == 2) ? v : o;
    local = j & ((1 << 20) - 1);
  }
  const float4 a = *(const float4*)(src + local);
  const float4 b = *(const float4*)(src + local + 4);
  uint4 r;
  r.x = pack_bf2(a.x, a.y); r.y = pack_bf2(a.z, a.w);
  r.z = pack_bf2(b.x, b.y); r.w = pack_bf2(b.z, b.w);
  *(uint4*)(dst + i) = r;
}

// ---------------------------------------------------------------------------
// 256x256-tile 8-phase QKV GEMM (HK-style schedule in plain HIP).
// C[m,n] = sum_k A[m,k]*B[n,k], K=1024, BK=64, 512 thr = 8 waves (2M x 4N),
// per-wave 128x64 output. LDS 128 KiB dbuf. 4 phases per K-tile, each:
// {ds_read frag subtile | stage 1 half-tile | barrier | lgkmcnt(0) |
//  setprio(1) 16 MFMA setprio(0) | barrier}. Counted vmcnt(4) once per
// K-tile (never 0 until tail). Granule-XOR LDS swizzle (same as gemm128):
// granule (16B) slot s of row r holds k-group s^(r&7).
// Staging lead (derived race-free): prologue = tile0{A0,B0,A1,B1} +
// tile1{A0,B0}; ph1->A1(t+1), ph2->B1(t+1), ph3->A0(t+2), ph4->B0(t+2).
// Region-read windows: A0,B0 read in ph1 only (B-frags held in regs),
// B1 in ph2, A1 in ph3; every clobbering gload issues >=1 barrier-pair
// after the last read of its region. At each ph4 vmcnt(4): queue worst case
// = 12 loads, oldest 8 = all of tile t+1 -> guaranteed landed.
// Fused epilogue -> Q (scaled, [bh][s][dh]), K ([bh][s][dh]), V^T ([bh][dh][s]).
// ---------------------------------------------------------------------------
template<int QM, int QN>
__device__ __forceinline__ void mm_phase(f32x4 (&acc)[8][4],
                                         const bf16x8 (&A)[4][2],
                                         const bf16x8 (&B)[2][2]) {
  __builtin_amdgcn_s_setprio(1);
#pragma unroll
  for (int i = 0; i < 4; ++i)
#pragma unroll
    for (int j = 0; j < 2; ++j) {
      f32x4& d = acc[QM * 4 + i][QN * 2 + j];
      d = __builtin_amdgcn_mfma_f32_16x16x32_bf16(A[i][0], B[j][0], d, 0, 0, 0);
      d = __builtin_amdgcn_mfma_f32_16x16x32_bf16(A[i][1], B[j][1], d, 0, 0, 0);
    }
  __builtin_amdgcn_s_setprio(0);
}

__global__ __launch_bounds__(512, 2) void gemm256_qkv(const u16* __restrict__ A,
                                                      const u16* __restrict__ Bw,
                                                      u16* __restrict__ Cv) {
  __shared__ __align__(16) u16 As[2][256 * 64];
  __shared__ __align__(16) u16 Bs[2][256 * 64];
  const int tid = threadIdx.x;
  const int lane = tid & 63;
  const int wave = tid >> 6;                 // 0..7
  const int col = lane & 15, quad = lane >> 4;
  const int wr = wave >> 2;                  // 0..1 (M)
  const int wc = wave & 3;                   // 0..3 (N)
  const int m_blk = blockIdx.x * 256, n_blk = blockIdx.y * 256;

  const int srow = tid >> 3;                 // 0..63
  const int skg = (tid & 7) ^ (srow & 7);
  const int lofs = tid * 8;                  // u16: == base + lane*16B per wave
  const u16* Ag = A + (size_t)(m_blk + srow) * DM + skg * 8;
  const u16* Bg = Bw + (size_t)(n_blk + srow) * DM + skg * 8;

  f32x4 acc[8][4];
#pragma unroll
  for (int i = 0; i < 8; ++i)
#pragma unroll
    for (int j = 0; j < 4; ++j) acc[i][j] = (f32x4){0.f, 0.f, 0.f, 0.f};

  const int c0 = (quad ^ (col & 7)) * 8;
  const int c1 = c0 ^ 32;

#define STG_A(hm, tt) do {                                                   \
    gload16(Ag + (size_t)((hm) * 128) * DM + (tt) * 64,                      \
            &As[(tt) & 1][(hm) * 8192 + lofs]);                              \
    gload16(Ag + (size_t)((hm) * 128 + 64) * DM + (tt) * 64,                 \
            &As[(tt) & 1][(hm) * 8192 + 4096 + lofs]);                       \
  } while (0)
#define STG_B(hn, tt) do {                                                   \
    gload16(Bg + (size_t)((hn) * 128) * DM + (tt) * 64,                      \
            &Bs[(tt) & 1][(hn) * 8192 + lofs]);                              \
    gload16(Bg + (size_t)((hn) * 128 + 64) * DM + (tt) * 64,                 \
            &Bs[(tt) & 1][(hn) * 8192 + 4096 + lofs]);                       \
  } while (0)

  // prologue: tile0 {A0,B0,A1,B1} + tile1 {A0,B0} = 12 loads; wait oldest 8.
  STG_A(0, 0); STG_B(0, 0); STG_A(1, 0); STG_B(1, 0);
  STG_A(0, 1); STG_B(0, 1);
  asm volatile("s_waitcnt vmcnt(4)" ::: "memory");
  __builtin_amdgcn_s_barrier();

  bf16x8 af[4][2], bq0[2][2], bq1[2][2];

  for (int t = 0; t < NT; ++t) {
    const u16* Ab = As[t & 1];
    const u16* Bb = Bs[t & 1];

    // ---- phase 1: quadrant (qm=0, qn=0); reads A0 + B0; stage A1(t+1) ----
#pragma unroll
    for (int i = 0; i < 4; ++i) {
      const int ro = (wr * 64 + i * 16 + col) * 64;
      af[i][0] = *(const bf16x8*)&Ab[ro + c0];
      af[i][1] = *(const bf16x8*)&Ab[ro + c1];
    }
#pragma unroll
    for (int j = 0; j < 2; ++j) {
      const int ro = (wc * 32 + j * 16 + col) * 64;
      bq0[j][0] = *(const bf16x8*)&Bb[ro + c0];
      bq0[j][1] = *(const bf16x8*)&Bb[ro + c1];
    }
    if (t + 1 < NT) STG_A(1, t + 1);
    __builtin_amdgcn_s_barrier();
    asm volatile("s_waitcnt lgkmcnt(0)" ::: "memory");
    mm_phase<0, 0>(acc, af, bq0);
    __builtin_amdgcn_s_barrier();

    // ---- phase 2: (qm=0, qn=1); reads B1 (A0 held); stage B1(t+1) ----
#pragma unroll
    for (int j = 0; j < 2; ++j) {
      const int ro = (128 + wc * 32 + j * 16 + col) * 64;
      bq1[j][0] = *(const bf16x8*)&Bb[ro + c0];
      bq1[j][1] = *(const bf16x8*)&Bb[ro + c1];
    }
    if (t + 1 < NT) STG_B(1, t + 1);
    __builtin_amdgcn_s_barrier();
    asm volatile("s_waitcnt lgkmcnt(0)" ::: "memory");
    mm_phase<0, 1>(acc, af, bq1);
    __builtin_amdgcn_s_barrier();

    // ---- phase 3: (qm=1, qn=0); reads A1 (B0 held); stage A0(t+2) ----
#pragma unroll
    for (int i = 0; i < 4; ++i) {
      const int ro = (128 + wr * 64 + i * 16 + col) * 64;
      af[i][0] = *(const bf16x8*)&Ab[ro + c0];
      af[i][1] = *(const bf16x8*)&Ab[ro + c1];
    }
    if (t + 2 < NT) STG_A(0, t + 2);
    __builtin_amdgcn_s_barrier();
    asm volatile("s_waitcnt lgkmcnt(0)" ::: "memory");
    mm_phase<1, 0>(acc, af, bq0);
    __builtin_amdgcn_s_barrier();

    // ---- phase 4: (qm=1, qn=1); no reads (A1,B1 held); stage B0(t+2) ----
    if (t + 2 < NT) STG_B(0, t + 2);
    __builtin_amdgcn_s_barrier();
    mm_phase<1, 1>(acc, af, bq1);
    if (t < NT - 2) { asm volatile("s_waitcnt vmcnt(4)" ::: "memory"); }
    else            { asm volatile("s_waitcnt vmcnt(0)" ::: "memory"); }
    __builtin_amdgcn_s_barrier();
  }
#undef STG_A
#undef STG_B

  // epilogue. C/D: col = lane&15 (n), row = quad*4+reg (m).
  // n = n_blk + qn*128 + wc*32 + j*16 + col; m = m_blk + qm*128 + wr*64 + i*16 + quad*4 + r
  const int which = n_blk >> 10;             // uniform per block (256 | 1024)
#pragma unroll
  for (int mi = 0; mi < 8; ++mi) {
#pragma unroll
    for (int nj = 0; nj < 4; ++nj) {
      const int n = n_blk + (nj >> 1) * 128 + wc * 32 + (nj & 1) * 16 + col;
      const int nn = n & 1023;
      const int h = nn >> 6, dh = nn & 63;
      u16* dst = Cv + (size_t)which * SZX;
      const int m0 = m_blk + (mi >> 2) * 128 + wr * 64 + (mi & 3) * 16 + quad * 4;
      const int b = m0 >> 11;
      if (which == 2) {                      // V^T [bh][dh][s]
        uint2 pk;
        pk.x = pack_bf2(acc[mi][nj][0], acc[mi][nj][1]);
        pk.y = pack_bf2(acc[mi][nj][2], acc[mi][nj][3]);
        *(uint2*)&dst[((size_t)((b * NH + h) * DH + dh)) * S_LEN + (m0 & 2047)] = pk;
      } else {
        const float sc = (which == 0) ? QSCALE : 1.0f;
#pragma unroll
        for (int r = 0; r < 4; ++r) {
          const int m = m0 + r, s = m & 2047;
          dst[((size_t)(b * NH + h) * S_LEN + s) * DH + dh] = f2bf(acc[mi][nj][r] * sc);
        }
      }
    }
  }
}

// ---------------------------------------------------------------------------
// 128x128-tile GEMM, C[m,n] = sum_k A[m,k]*B[n,k], K = 1024, BK = 64.
// (kept for the O-projection: N=1024 gives 512 blocks here vs 128 at 256²)
// ---------------------------------------------------------------------------
template<int MODE>
__global__ __launch_bounds__(256) void gemm128(const u16* __restrict__ A,
                                               const u16* __restrict__ Bw,
                                               void* __restrict__ Cv) {
  __shared__ __align__(16) u16 As[128 * 64];
  __shared__ __align__(16) u16 Bs[128 * 64];
  const int tid = threadIdx.x;
  const int lane = tid & 63;
  const int wave = tid >> 6;
  const int col = lane & 15, quad = lane >> 4;
  const int wm = (wave & 1) * 64, wn = (wave >> 1) * 64;
  const int m_blk = blockIdx.x * 128, n_blk = blockIdx.y * 128;

  const int srow = tid >> 3;
  const int skg = (tid & 7) ^ (srow & 7);
  const u16* Ag = A + (size_t)(m_blk + srow) * DM + skg * 8;
  const u16* Bg = Bw + (size_t)(n_blk + srow) * DM + skg * 8;

  f32x4 acc[4][4];
#pragma unroll
  for (int i = 0; i < 4; ++i)
#pragma unroll
    for (int j = 0; j < 4; ++j) acc[i][j] = (f32x4){0.f, 0.f, 0.f, 0.f};

  const int c0 = (quad ^ (col & 7)) * 8;   // k-group quad
  const int c1 = c0 ^ 32;                  // k-group quad+4

  for (int k0 = 0; k0 < DM; k0 += 64) {
#pragma unroll
    for (int i = 0; i < 4; ++i) {
      gload16(Ag + (size_t)(32 * i) * DM + k0, &As[tid * 8 + i * 2048]);
      gload16(Bg + (size_t)(32 * i) * DM + k0, &Bs[tid * 8 + i * 2048]);
    }
    __syncthreads();
    bf16x8 af[4], bf[4];
#pragma unroll
    for (int i = 0; i < 4; ++i)
      af[i] = *(const bf16x8*)&As[(wm + i * 16 + col) * 64 + c0];
#pragma unroll
    for (int j = 0; j < 4; ++j)
      bf[j] = *(const bf16x8*)&Bs[(wn + j * 16 + col) * 64 + c0];
#pragma unroll
    for (int i = 0; i < 4; ++i)
#pragma unroll
      for (int j = 0; j < 4; ++j)
        acc[i][j] = __builtin_amdgcn_mfma_f32_16x16x32_bf16(af[i], bf[j], acc[i][j], 0, 0, 0);
#pragma unroll
    for (int i = 0; i < 4; ++i)
      af[i] = *(const bf16x8*)&As[(wm + i * 16 + col) * 64 + c1];
#pragma unroll
    for (int j = 0; j < 4; ++j)
      bf[j] = *(const bf16x8*)&Bs[(wn + j * 16 + col) * 64 + c1];
#pragma unroll
    for (int i = 0; i < 4; ++i)
#pragma unroll
      for (int j = 0; j < 4; ++j)
        acc[i][j] = __builtin_amdgcn_mfma_f32_16x16x32_bf16(af[i], bf[j], acc[i][j], 0, 0, 0);
    __syncthreads();
  }

  // epilogue. C/D: col = lane&15 (n), row = quad*4+reg (m).
#pragma unroll
  for (int i = 0; i < 4; ++i) {
#pragma unroll
    for (int j = 0; j < 4; ++j) {
      const int n = n_blk + wn + j * 16 + col;
      if (MODE == 0) {
        const int which = n >> 10;            // 0=Q 1=K 2=V (uniform per wave)
        const int nn = n & 1023;
        const int h = nn >> 6, dh = nn & 63;
        u16* dst = (u16*)Cv + (size_t)which * SZX;
        const int m0 = m_blk + wm + i * 16 + quad * 4;
        const int b = m0 >> 11;
        if (which == 2) {                     // V^T [bh][dh][s]
          uint2 pk;
          pk.x = pack_bf2(acc[i][j][0], acc[i][j][1]);
          pk.y = pack_bf2(acc[i][j][2], acc[i][j][3]);
          *(uint2*)&dst[((size_t)((b * NH + h) * DH + dh)) * S_LEN + (m0 & 2047)] = pk;
        } else {
          const float sc = (which == 0) ? QSCALE : 1.0f;
#pragma unroll
          for (int r = 0; r < 4; ++r) {
            const int m = m0 + r, s = m & 2047;
            dst[((size_t)(b * NH + h) * S_LEN + s) * DH + dh] = f2bf(acc[i][j][r] * sc);
          }
        }
      } else {
#pragma unroll
        for (int r = 0; r < 4; ++r) {
          const int m = m_blk + wm + i * 16 + quad * 4 + r;
          ((float*)Cv)[(size_t)m * DM + n] = acc[i][j][r];
        }
      }
    }
  }
}

// ---------------------------------------------------------------------------
// Flash attention, causal, S^T form, PAIRED q-tiles, dbuf K/V, no online max.
// Branchless MERGED H+L step for kt <= qtL. Unchanged this round.
// ---------------------------------------------------------------------------
template<bool DIAG_H, bool DIAG_L, bool WITH_L>
__device__ __forceinline__ void stepHL(const u16* __restrict__ Ksb,
                                       const u16* __restrict__ Vsb,
                                       u16* __restrict__ Pw,
                                       bf16x8 qH0, bf16x8 qH1,
                                       bf16x8 qL0, bf16x8 qL1,
                                       f32x4& lH, f32x4* oH,
                                       f32x4& lL, f32x4* oL,
                                       f32x4 zero4, bf16x8 ones,
                                       int c0, int c1, int col, int quad,
                                       int q_l) {
  const int colc = col & 7;
  f32x4 sH[4], sL[4];
#pragma unroll
  for (int t = 0; t < 4; ++t) {
    const int row = (t * 16 + col) * 64;
    const bf16x8 kf0 = *(const bf16x8*)&Ksb[row + c0];
    const bf16x8 kf1 = *(const bf16x8*)&Ksb[row + c1];
    f32x4 z = __builtin_amdgcn_mfma_f32_16x16x32_bf16(kf0, qH0, zero4, 0, 0, 0);
    sH[t] = __builtin_amdgcn_mfma_f32_16x16x32_bf16(kf1, qH1, z, 0, 0, 0);
    if (WITH_L) {
      f32x4 y = __builtin_amdgcn_mfma_f32_16x16x32_bf16(kf0, qL0, zero4, 0, 0, 0);
      sL[t] = __builtin_amdgcn_mfma_f32_16x16x32_bf16(kf1, qL1, y, 0, 0, 0);
    }
  }
#pragma unroll
  for (int t = 0; t < 4; ++t)
#pragma unroll
    for (int r = 0; r < 4; ++r) {
      if (DIAG_H && (t * 16 + quad * 4 + r) > q_l) sH[t][r] = -1e30f;
      sH[t][r] = fast_exp2(sH[t][r]);
      if (WITH_L) {
        if (DIAG_L && (t * 16 + quad * 4 + r) > q_l) sL[t][r] = -1e30f;
        sL[t][r] = fast_exp2(sL[t][r]);
      }
    }
  // ---- P_H round trip + l_H + PV_H ----
#pragma unroll
  for (int t = 0; t < 4; ++t) {
    uint2 pk;
    pk.x = pack_bf2(sH[t][0], sH[t][1]);
    pk.y = pack_bf2(sH[t][2], sH[t][3]);
    const int pg = (((t * 2) + (quad >> 1)) ^ colc) * 8 + (quad & 1) * 4;
    *(uint2*)&Pw[col * 64 + pg] = pk;
  }
  {
    const bf16x8 pf0 = *(const bf16x8*)&Pw[col * 64 + ((quad ^ colc) * 8)];
    const bf16x8 pf1 = *(const bf16x8*)&Pw[col * 64 + (((4 + quad) ^ colc) * 8)];
    lH = __builtin_amdgcn_mfma_f32_16x16x32_bf16(ones, pf0, lH, 0, 0, 0);
    lH = __builtin_amdgcn_mfma_f32_16x16x32_bf16(ones, pf1, lH, 0, 0, 0);
#pragma unroll
    for (int t = 0; t < 4; ++t) {
      const int row = (t * 16 + col) * 64;
      const bf16x8 vf0 = *(const bf16x8*)&Vsb[row + c0];
      const bf16x8 vf1 = *(const bf16x8*)&Vsb[row + c1];
      oH[t] = __builtin_amdgcn_mfma_f32_16x16x32_bf16(vf0, pf0, oH[t], 0, 0, 0);
      oH[t] = __builtin_amdgcn_mfma_f32_16x16x32_bf16(vf1, pf1, oH[t], 0, 0, 0);
    }
  }
  // ---- P_L round trip + l_L + PV_L ----
  if (WITH_L) {
#pragma unroll
    for (int t = 0; t < 4; ++t) {
      uint2 pk;
      pk.x = pack_bf2(sL[t][0], sL[t][1]);
      pk.y = pack_bf2(sL[t][2], sL[t][3]);
      const int pg = (((t * 2) + (quad >> 1)) ^ colc) * 8 + (quad & 1) * 4;
      *(uint2*)&Pw[col * 64 + pg] = pk;
    }
    const bf16x8 pf0 = *(const bf16x8*)&Pw[col * 64 + ((quad ^ colc) * 8)];
    const bf16x8 pf1 = *(const bf16x8*)&Pw[col * 64 + (((4 + quad) ^ colc) * 8)];
    lL = __builtin_amdgcn_mfma_f32_16x16x32_bf16(ones, pf0, lL, 0, 0, 0);
    lL = __builtin_amdgcn_mfma_f32_16x16x32_bf16(ones, pf1, lL, 0, 0, 0);
#pragma unroll
    for (int t = 0; t < 4; ++t) {
      const int row = (t * 16 + col) * 64;
      const bf16x8 vf0 = *(const bf16x8*)&Vsb[row + c0];
      const bf16x8 vf1 = *(const bf16x8*)&Vsb[row + c1];
      oL[t] = __builtin_amdgcn_mfma_f32_16x16x32_bf16(vf0, pf0, oL[t], 0, 0, 0);
      oL[t] = __builtin_amdgcn_mfma_f32_16x16x32_bf16(vf1, pf1, oL[t], 0, 0, 0);
    }
  }
}

__global__ __launch_bounds__(256) void attn_kernel(const u16* __restrict__ Qg,
                                                   const u16* __restrict__ Kg,
                                                   const u16* __restrict__ Vtg,
                                                   u16* __restrict__ AO) {
  __shared__ __align__(16) u16 Ks[2][64 * 64];     // dbuf, swizzled [kv][dh]
  __shared__ __align__(16) u16 Vs[2][64 * 64];     // dbuf, swizzled [dh][kv]
  __shared__ __align__(16) u16 Ps[4][16 * 64];     // per-wave, XOR-swizzled

  const int id = blockIdx.x;
  const int k9 = id >> 3;                 // 0..127
  const int qtH = 16 + (k9 & 15);         // 16..31
  const int qtL = 31 - qtH;               // 15..0
  const int bh = ((id & 7) << 3) | (k9 >> 4);   // 0..63
  const int tid = threadIdx.x, lane = tid & 63, wave = tid >> 6;
  const int col = lane & 15, quad = lane >> 4;

  const u16* Qb = Qg + (size_t)bh * S_LEN * DH;
  const u16* Kb = Kg + (size_t)bh * S_LEN * DH;
  const u16* Vb = Vtg + (size_t)bh * DH * S_LEN;

  // Q B-frags: n = q = col, k = dh = quad*8+j (+32)
  const u16* qrowH = Qb + (size_t)(qtH * 64 + wave * 16 + col) * DH + quad * 8;
  const u16* qrowL = Qb + (size_t)(qtL * 64 + wave * 16 + col) * DH + quad * 8;
  const bf16x8 qH0 = *(const bf16x8*)(qrowH);
  const bf16x8 qH1 = *(const bf16x8*)(qrowH + 32);
  const bf16x8 qL0 = *(const bf16x8*)(qrowL);
  const bf16x8 qL1 = *(const bf16x8*)(qrowL + 32);

  const f32x4 zero4 = (f32x4){0.f, 0.f, 0.f, 0.f};
  const bf16x8 ones = (bf16x8){0x3F80, 0x3F80, 0x3F80, 0x3F80,
                               0x3F80, 0x3F80, 0x3F80, 0x3F80};   // bf16 1.0

  f32x4 lH = zero4, lL = zero4;
  f32x4 oH[4], oL[4];
#pragma unroll
  for (int t = 0; t < 4; ++t) { oH[t] = zero4; oL[t] = zero4; }

  // staging granules: row = g>>3, slot = g&7, source grp = slot^(row&7).
  const int sr0 = tid >> 3;
  const int sk0 = (tid & 7) ^ (sr0 & 7);
  const u16* K0 = Kb + (size_t)sr0 * DH + sk0 * 8;
  const u16* K1 = Kb + (size_t)(sr0 + 32) * DH + sk0 * 8;
  const u16* V0 = Vb + (size_t)sr0 * S_LEN + sk0 * 8;
  const u16* V1 = Vb + (size_t)(sr0 + 32) * S_LEN + sk0 * 8;

  const int c0 = (quad ^ (col & 7)) * 8;
  const int c1 = c0 ^ 32;
  const int q_l = wave * 16 + col;
  u16* Pw = &Ps[wave][0];

  // prologue: stage tile 0 into buffer 0
  gload16(K0, &Ks[0][tid * 8]);
  gload16(K1, &Ks[0][2048 + tid * 8]);
  gload16(V0, &Vs[0][tid * 8]);
  gload16(V1, &Vs[0][2048 + tid * 8]);

#define PREFETCH(nk) do {                                   \
    const int nb_ = (nk) & 1;                               \
    gload16(K0 + (size_t)(nk) * 64 * DH, &Ks[nb_][tid * 8]);\
    gload16(K1 + (size_t)(nk) * 64 * DH, &Ks[nb_][2048 + tid * 8]); \
    gload16(V0 + (nk) * 64, &Vs[nb_][tid * 8]);             \
    gload16(V1 + (nk) * 64, &Vs[nb_][2048 + tid * 8]);      \
  } while (0)

  int kt = 0;
  // phase 1a: merged H+L, no diag (kt < qtL); prefetch always valid
  for (; kt < qtL; ++kt) {
    __syncthreads();
    PREFETCH(kt + 1);
    stepHL<false, false, true>(&Ks[kt & 1][0], &Vs[kt & 1][0], Pw,
                               qH0, qH1, qL0, qL1, lH, oH, lL, oL,
                               zero4, ones, c0, c1, col, quad, q_l);
  }
  // phase 1b: kt == qtL: merged, L hits its diagonal (qtL < qtH always)
  {
    __syncthreads();
    PREFETCH(kt + 1);
    stepHL<false, true, true>(&Ks[kt & 1][0], &Vs[kt & 1][0], Pw,
                              qH0, qH1, qL0, qL1, lH, oH, lL, oL,
                              zero4, ones, c0, c1, col, quad, q_l);
    ++kt;
  }
  // phase 2: H only, no diag
  for (; kt < qtH; ++kt) {
    __syncthreads();
    PREFETCH(kt + 1);
    stepHL<false, false, false>(&Ks[kt & 1][0], &Vs[kt & 1][0], Pw,
                                qH0, qH1, qL0, qL1, lH, oH, lL, oL,
                                zero4, ones, c0, c1, col, quad, q_l);
  }
  // final: kt == qtH: H diagonal, no prefetch
  {
    __syncthreads();
    stepHL<true, false, false>(&Ks[kt & 1][0], &Vs[kt & 1][0], Pw,
                               qH0, qH1, qL0, qL1, lH, oH, lL, oL,
                               zero4, ones, c0, c1, col, quad, q_l);
  }
#undef PREFETCH

  // epilogue: lacc[0] holds the full l for this lane's q = col.
  const int b = bh >> 4, h = bh & 15;
  {
    const float inv = __builtin_amdgcn_rcpf(lH[0]);
    const size_t base = (size_t)(b * S_LEN + qtH * 64 + q_l) * DM + h * DH;
#pragma unroll
    for (int t = 0; t < 4; ++t) {
      uint2 pk;
      pk.x = pack_bf2(oH[t][0] * inv, oH[t][1] * inv);
      pk.y = pack_bf2(oH[t][2] * inv, oH[t][3] * inv);
      *(uint2*)&AO[base + t * 16 + quad * 4] = pk;
    }
  }
  {
    const float inv = __builtin_amdgcn_rcpf(lL[0]);
    const size_t base = (size_t)(b * S_LEN + qtL * 64 + q_l) * DM + h * DH;
#pragma unroll
    for (int t = 0; t < 4; ++t) {
      uint2 pk;
      pk.x = pack_bf2(oL[t][0] * inv, oL[t][1] * inv);
      pk.y = pack_bf2(oL[t][2] * inv, oL[t][3] * inv);
      *(uint2*)&AO[base + t * 16 + quad * 4] = pk;
    }
  }
}

extern "C" void kernel_launch(void* const* d_in, const int* in_sizes, int n_in,
                              void* d_out, int out_size, void* d_ws, size_t ws_size,
                              hipStream_t stream) {
  const float* X  = (const float*)d_in[0];
  const float* Wq = (const float*)d_in[1];
  const float* Wk = (const float*)d_in[2];
  const float* Wv = (const float*)d_in[3];
  const float* Wo = (const float*)d_in[4];

  u16* Xb   = (u16*)d_ws;            // 8Mi  (reused as AO after QKV)
  u16* Wqkv = Xb + SZX;              // 3Mi  (Wq|Wk|Wv contiguous)
  u16* Wob  = Wqkv + 3 * SZW;        // 1Mi  (contiguous after Wqkv)
  u16* Qb   = Wob + SZW;             // 8Mi  [bh][s][dh], pre-scaled QSCALE
  u16* Kb   = Qb + SZX;              // 8Mi  [bh][s][dh]
  u16* VT   = Kb + SZX;              // 8Mi  [bh][dh][s]
  u16* AO   = Xb;

  cast_all<<<(int)((SZX + 4 * SZW) / 8 / 256), 256, 0, stream>>>(X, Wq, Wk, Wv, Wo, Xb);

  gemm256_qkv<<<dim3(M_TOK / 256, 3 * DM / 256), 512, 0, stream>>>(Xb, Wqkv, Qb);

  attn_kernel<<<dim3(1024), 256, 0, stream>>>(Qb, Kb, VT, AO);

  gemm128<1><<<dim3(M_TOK / 128, DM / 128), 256, 0, stream>>>(AO, Wob, d_out);
}

// Round 2
// 251.463 us; speedup vs baseline: 1.0139x; 1.0139x over previous
//
#include <hip/hip_runtime.h>

#define S_LEN 2048
#define NH 16
#define DH 64
#define DM 1024
#define M_TOK 8192              // B*S
#define SZX ((size_t)M_TOK * DM)   // 8 Mi elems
#define SZW ((size_t)DM * DM)      // 1 Mi elems (2^20)

typedef unsigned short u16;
typedef unsigned int u32;
typedef __attribute__((ext_vector_type(8))) short bf16x8;   // 8 bf16 = 4 VGPRs
typedef __attribute__((ext_vector_type(4))) float f32x4;

// round-half-up bf16 (error bound == RNE except exact ties)
__device__ __forceinline__ u16 f2bf(float f) {
  union { float f; u32 u; } v; v.f = f;
  return (u16)((v.u + 0x8000u) >> 16);
}
// pack two floats -> (bf16(y)<<16)|bf16(x) in 2 adds + 1 v_perm
__device__ __forceinline__ u32 pack_bf2(float x, float y) {
  union { float f; u32 u; } a, b; a.f = x; b.f = y;
  return __builtin_amdgcn_perm(b.u + 0x8000u, a.u + 0x8000u, 0x07060302u);
}
__device__ __forceinline__ float fast_exp2(float x) {
  float r; asm("v_exp_f32 %0, %1" : "=v"(r) : "v"(x)); return r;
}
// async global->LDS, 16B/lane. dest = wave-uniform base + lane*16.
__device__ __forceinline__ void gload16(const u16* g, u16* l) {
  __builtin_amdgcn_global_load_lds((const __attribute__((address_space(1))) void*)g,
                                   (__attribute__((address_space(3))) void*)l,
                                   16, 0, 0);
}

#define QSCALE 0.18033688f   // 1/sqrt(64) * log2(e)

// Fused cast: X (8Mi) + Wq|Wk|Wv|Wo (4 x 1Mi) -> contiguous bf16 dst.
__global__ __launch_bounds__(256) void cast_all(const float* __restrict__ X,
                                                const float* __restrict__ q,
                                                const float* __restrict__ k,
                                                const float* __restrict__ v,
                                                const float* __restrict__ o,
                                                u16* __restrict__ dst) {
  const int i = (blockIdx.x * 256 + threadIdx.x) * 8;   // [0, 12Mi)
  const float* src;
  int local;
  if (i < (int)SZX) { src = X; local = i; }
  else {
    const int j = i - (int)SZX;
    const int region = j >> 20;
    src = (region == 0) ? q : (region == 1) ? k : (region == 2) ? v : o;
    local = j & ((1 << 20) - 1);
  }
  const float4 a = *(const float4*)(src + local);
  const float4 b = *(const float4*)(src + local + 4);
  uint4 r;
  r.x = pack_bf2(a.x, a.y); r.y = pack_bf2(a.z, a.w);
  r.z = pack_bf2(b.x, b.y); r.w = pack_bf2(b.z, b.w);
  *(uint4*)(dst + i) = r;
}

// ---------------------------------------------------------------------------
// 128x128-tile GEMM, C[m,n] = sum_k A[m,k]*B[n,k], K = 1024, BK = 64.
// 32 KB LDS, 8 global_load_lds + 32 MFMA per barrier pair. XOR swizzle:
// granule (16B) g: row = g>>3, slot = g&7, source kgrp = slot ^ (row&7).
// MODE 0: N=3072 fused QKV epilogue -> Q (scaled QSCALE, [bh][s][dh]),
//         K ([bh][s][dh]), V^T ([bh][dh][s]), bf16. MODE 1: fp32 [M,DM].
// (r10: the 256x256 8-phase port regressed ~8us here -- 384 blocks at 1
//  block/CU gives a 2-tau tail at this M,N and K=1024 is too short to
//  amortize its pipeline; reverted to this known-good structure.)
// ---------------------------------------------------------------------------
template<int MODE>
__global__ __launch_bounds__(256) void gemm128(const u16* __restrict__ A,
                                               const u16* __restrict__ Bw,
                                               void* __restrict__ Cv) {
  __shared__ __align__(16) u16 As[128 * 64];
  __shared__ __align__(16) u16 Bs[128 * 64];
  const int tid = threadIdx.x;
  const int lane = tid & 63;
  const int wave = tid >> 6;
  const int col = lane & 15, quad = lane >> 4;
  const int wm = (wave & 1) * 64, wn = (wave >> 1) * 64;
  const int m_blk = blockIdx.x * 128, n_blk = blockIdx.y * 128;

  const int srow = tid >> 3;
  const int skg = (tid & 7) ^ (srow & 7);
  const u16* Ag = A + (size_t)(m_blk + srow) * DM + skg * 8;
  const u16* Bg = Bw + (size_t)(n_blk + srow) * DM + skg * 8;

  f32x4 acc[4][4];
#pragma unroll
  for (int i = 0; i < 4; ++i)
#pragma unroll
    for (int j = 0; j < 4; ++j) acc[i][j] = (f32x4){0.f, 0.f, 0.f, 0.f};

  const int c0 = (quad ^ (col & 7)) * 8;   // k-group quad
  const int c1 = c0 ^ 32;                  // k-group quad+4

  for (int k0 = 0; k0 < DM; k0 += 64) {
#pragma unroll
    for (int i = 0; i < 4; ++i) {
      gload16(Ag + (size_t)(32 * i) * DM + k0, &As[tid * 8 + i * 2048]);
      gload16(Bg + (size_t)(32 * i) * DM + k0, &Bs[tid * 8 + i * 2048]);
    }
    __syncthreads();
    bf16x8 af[4], bf[4];
#pragma unroll
    for (int i = 0; i < 4; ++i)
      af[i] = *(const bf16x8*)&As[(wm + i * 16 + col) * 64 + c0];
#pragma unroll
    for (int j = 0; j < 4; ++j)
      bf[j] = *(const bf16x8*)&Bs[(wn + j * 16 + col) * 64 + c0];
#pragma unroll
    for (int i = 0; i < 4; ++i)
#pragma unroll
      for (int j = 0; j < 4; ++j)
        acc[i][j] = __builtin_amdgcn_mfma_f32_16x16x32_bf16(af[i], bf[j], acc[i][j], 0, 0, 0);
#pragma unroll
    for (int i = 0; i < 4; ++i)
      af[i] = *(const bf16x8*)&As[(wm + i * 16 + col) * 64 + c1];
#pragma unroll
    for (int j = 0; j < 4; ++j)
      bf[j] = *(const bf16x8*)&Bs[(wn + j * 16 + col) * 64 + c1];
#pragma unroll
    for (int i = 0; i < 4; ++i)
#pragma unroll
      for (int j = 0; j < 4; ++j)
        acc[i][j] = __builtin_amdgcn_mfma_f32_16x16x32_bf16(af[i], bf[j], acc[i][j], 0, 0, 0);
    __syncthreads();
  }

  // epilogue. C/D: col = lane&15 (n), row = quad*4+reg (m).
#pragma unroll
  for (int i = 0; i < 4; ++i) {
#pragma unroll
    for (int j = 0; j < 4; ++j) {
      const int n = n_blk + wn + j * 16 + col;
      if (MODE == 0) {
        const int which = n >> 10;            // 0=Q 1=K 2=V (uniform per wave)
        const int nn = n & 1023;
        const int h = nn >> 6, dh = nn & 63;
        u16* dst = (u16*)Cv + (size_t)which * SZX;
        const int m0 = m_blk + wm + i * 16 + quad * 4;
        const int b = m0 >> 11;
        if (which == 2) {                     // V^T [bh][dh][s]
          uint2 pk;
          pk.x = pack_bf2(acc[i][j][0], acc[i][j][1]);
          pk.y = pack_bf2(acc[i][j][2], acc[i][j][3]);
          *(uint2*)&dst[((size_t)((b * NH + h) * DH + dh)) * S_LEN + (m0 & 2047)] = pk;
        } else {
          const float sc = (which == 0) ? QSCALE : 1.0f;
#pragma unroll
          for (int r = 0; r < 4; ++r) {
            const int m = m0 + r, s = m & 2047;
            dst[((size_t)(b * NH + h) * S_LEN + s) * DH + dh] = f2bf(acc[i][j][r] * sc);
          }
        }
      } else {
#pragma unroll
        for (int r = 0; r < 4; ++r) {
          const int m = m_blk + wm + i * 16 + quad * 4 + r;
          ((float*)Cv)[(size_t)m * DM + n] = acc[i][j][r];
        }
      }
    }
  }
}

// ---------------------------------------------------------------------------
// Flash attention, causal, S^T form, dbuf K/V, no online max.
// r10: ADJACENT q-tile pairing (qtH = 2p+1, qtL = 2p). Both strips share
// the same causal extent, so ~94% of steps are MERGED (vs 35% with the old
// qtH+qtL=31 pairing): steps/bh drop 392 -> 272. Block work now varies
// (2..32 steps); pair index is reversed so the longest blocks dispatch
// first (LPT packing; 4 blocks/CU co-residency absorbs the tail).
// Also r10: T5 s_setprio(1) around MFMA clusters.
// Grid: 1D 1024 with XCD-colocating swizzle (id%8 = bh>>3).
// ---------------------------------------------------------------------------
template<bool DIAG_H, bool DIAG_L, bool WITH_L>
__device__ __forceinline__ void stepHL(const u16* __restrict__ Ksb,
                                       const u16* __restrict__ Vsb,
                                       u16* __restrict__ Pw,
                                       bf16x8 qH0, bf16x8 qH1,
                                       bf16x8 qL0, bf16x8 qL1,
                                       f32x4& lH, f32x4* oH,
                                       f32x4& lL, f32x4* oL,
                                       f32x4 zero4, bf16x8 ones,
                                       int c0, int c1, int col, int quad,
                                       int q_l) {
  const int colc = col & 7;
  f32x4 sH[4], sL[4];
  __builtin_amdgcn_s_setprio(1);
#pragma unroll
  for (int t = 0; t < 4; ++t) {
    const int row = (t * 16 + col) * 64;
    const bf16x8 kf0 = *(const bf16x8*)&Ksb[row + c0];
    const bf16x8 kf1 = *(const bf16x8*)&Ksb[row + c1];
    f32x4 z = __builtin_amdgcn_mfma_f32_16x16x32_bf16(kf0, qH0, zero4, 0, 0, 0);
    sH[t] = __builtin_amdgcn_mfma_f32_16x16x32_bf16(kf1, qH1, z, 0, 0, 0);
    if (WITH_L) {
      f32x4 y = __builtin_amdgcn_mfma_f32_16x16x32_bf16(kf0, qL0, zero4, 0, 0, 0);
      sL[t] = __builtin_amdgcn_mfma_f32_16x16x32_bf16(kf1, qL1, y, 0, 0, 0);
    }
  }
  __builtin_amdgcn_s_setprio(0);
  // exp (both strips up front: exp_L is independent of the P_H round trip,
  // giving the scheduler VALU work to overlap with LDS waits)
#pragma unroll
  for (int t = 0; t < 4; ++t)
#pragma unroll
    for (int r = 0; r < 4; ++r) {
      if (DIAG_H && (t * 16 + quad * 4 + r) > q_l) sH[t][r] = -1e30f;
      sH[t][r] = fast_exp2(sH[t][r]);
      if (WITH_L) {
        if (DIAG_L && (t * 16 + quad * 4 + r) > q_l) sL[t][r] = -1e30f;
        sL[t][r] = fast_exp2(sL[t][r]);
      }
    }
  // ---- P_H round trip + l_H + PV_H ----
#pragma unroll
  for (int t = 0; t < 4; ++t) {
    uint2 pk;
    pk.x = pack_bf2(sH[t][0], sH[t][1]);
    pk.y = pack_bf2(sH[t][2], sH[t][3]);
    const int pg = (((t * 2) + (quad >> 1)) ^ colc) * 8 + (quad & 1) * 4;
    *(uint2*)&Pw[col * 64 + pg] = pk;
  }
  {
    const bf16x8 pf0 = *(const bf16x8*)&Pw[col * 64 + ((quad ^ colc) * 8)];
    const bf16x8 pf1 = *(const bf16x8*)&Pw[col * 64 + (((4 + quad) ^ colc) * 8)];
    __builtin_amdgcn_s_setprio(1);
    lH = __builtin_amdgcn_mfma_f32_16x16x32_bf16(ones, pf0, lH, 0, 0, 0);
    lH = __builtin_amdgcn_mfma_f32_16x16x32_bf16(ones, pf1, lH, 0, 0, 0);
#pragma unroll
    for (int t = 0; t < 4; ++t) {
      const int row = (t * 16 + col) * 64;
      const bf16x8 vf0 = *(const bf16x8*)&Vsb[row + c0];
      const bf16x8 vf1 = *(const bf16x8*)&Vsb[row + c1];
      oH[t] = __builtin_amdgcn_mfma_f32_16x16x32_bf16(vf0, pf0, oH[t], 0, 0, 0);
      oH[t] = __builtin_amdgcn_mfma_f32_16x16x32_bf16(vf1, pf1, oH[t], 0, 0, 0);
    }
    __builtin_amdgcn_s_setprio(0);
  }
  // ---- P_L round trip + l_L + PV_L ----
  if (WITH_L) {
#pragma unroll
    for (int t = 0; t < 4; ++t) {
      uint2 pk;
      pk.x = pack_bf2(sL[t][0], sL[t][1]);
      pk.y = pack_bf2(sL[t][2], sL[t][3]);
      const int pg = (((t * 2) + (quad >> 1)) ^ colc) * 8 + (quad & 1) * 4;
      *(uint2*)&Pw[col * 64 + pg] = pk;
    }
    const bf16x8 pf0 = *(const bf16x8*)&Pw[col * 64 + ((quad ^ colc) * 8)];
    const bf16x8 pf1 = *(const bf16x8*)&Pw[col * 64 + (((4 + quad) ^ colc) * 8)];
    __builtin_amdgcn_s_setprio(1);
    lL = __builtin_amdgcn_mfma_f32_16x16x32_bf16(ones, pf0, lL, 0, 0, 0);
    lL = __builtin_amdgcn_mfma_f32_16x16x32_bf16(ones, pf1, lL, 0, 0, 0);
#pragma unroll
    for (int t = 0; t < 4; ++t) {
      const int row = (t * 16 + col) * 64;
      const bf16x8 vf0 = *(const bf16x8*)&Vsb[row + c0];
      const bf16x8 vf1 = *(const bf16x8*)&Vsb[row + c1];
      oL[t] = __builtin_amdgcn_mfma_f32_16x16x32_bf16(vf0, pf0, oL[t], 0, 0, 0);
      oL[t] = __builtin_amdgcn_mfma_f32_16x16x32_bf16(vf1, pf1, oL[t], 0, 0, 0);
    }
    __builtin_amdgcn_s_setprio(0);
  }
}

__global__ __launch_bounds__(256) void attn_kernel(const u16* __restrict__ Qg,
                                                   const u16* __restrict__ Kg,
                                                   const u16* __restrict__ Vtg,
                                                   u16* __restrict__ AO) {
  __shared__ __align__(16) u16 Ks[2][64 * 64];     // dbuf, swizzled [kv][dh]
  __shared__ __align__(16) u16 Vs[2][64 * 64];     // dbuf, swizzled [dh][kv]
  __shared__ __align__(16) u16 Ps[4][16 * 64];     // per-wave, XOR-swizzled

  const int id = blockIdx.x;
  const int k9 = id >> 3;                 // 0..127
  // adjacent pairing, longest-first: p = 15 - (k9&15); qtH = 2p+1, qtL = 2p.
  const int qtH = 31 - 2 * (k9 & 15);     // 31,29,...,1 (odd)
  const int qtL = qtH - 1;                // 30,28,...,0 (even)
  const int bh = ((id & 7) << 3) | (k9 >> 4);   // 0..63
  const int tid = threadIdx.x, lane = tid & 63, wave = tid >> 6;
  const int col = lane & 15, quad = lane >> 4;

  const u16* Qb = Qg + (size_t)bh * S_LEN * DH;
  const u16* Kb = Kg + (size_t)bh * S_LEN * DH;
  const u16* Vb = Vtg + (size_t)bh * DH * S_LEN;

  // Q B-frags: n = q = col, k = dh = quad*8+j (+32)
  const u16* qrowH = Qb + (size_t)(qtH * 64 + wave * 16 + col) * DH + quad * 8;
  const u16* qrowL = Qb + (size_t)(qtL * 64 + wave * 16 + col) * DH + quad * 8;
  const bf16x8 qH0 = *(const bf16x8*)(qrowH);
  const bf16x8 qH1 = *(const bf16x8*)(qrowH + 32);
  const bf16x8 qL0 = *(const bf16x8*)(qrowL);
  const bf16x8 qL1 = *(const bf16x8*)(qrowL + 32);

  const f32x4 zero4 = (f32x4){0.f, 0.f, 0.f, 0.f};
  const bf16x8 ones = (bf16x8){0x3F80, 0x3F80, 0x3F80, 0x3F80,
                               0x3F80, 0x3F80, 0x3F80, 0x3F80};   // bf16 1.0

  f32x4 lH = zero4, lL = zero4;
  f32x4 oH[4], oL[4];
#pragma unroll
  for (int t = 0; t < 4; ++t) { oH[t] = zero4; oL[t] = zero4; }

  // staging granules: row = g>>3, slot = g&7, source grp = slot^(row&7).
  const int sr0 = tid >> 3;
  const int sk0 = (tid & 7) ^ (sr0 & 7);
  const u16* K0 = Kb + (size_t)sr0 * DH + sk0 * 8;
  const u16* K1 = Kb + (size_t)(sr0 + 32) * DH + sk0 * 8;
  const u16* V0 = Vb + (size_t)sr0 * S_LEN + sk0 * 8;
  const u16* V1 = Vb + (size_t)(sr0 + 32) * S_LEN + sk0 * 8;

  const int c0 = (quad ^ (col & 7)) * 8;
  const int c1 = c0 ^ 32;
  const int q_l = wave * 16 + col;
  u16* Pw = &Ps[wave][0];

  // prologue: stage tile 0 into buffer 0
  gload16(K0, &Ks[0][tid * 8]);
  gload16(K1, &Ks[0][2048 + tid * 8]);
  gload16(V0, &Vs[0][tid * 8]);
  gload16(V1, &Vs[0][2048 + tid * 8]);

#define PREFETCH(nk) do {                                   \
    const int nb_ = (nk) & 1;                               \
    gload16(K0 + (size_t)(nk) * 64 * DH, &Ks[nb_][tid * 8]);\
    gload16(K1 + (size_t)(nk) * 64 * DH, &Ks[nb_][2048 + tid * 8]); \
    gload16(V0 + (nk) * 64, &Vs[nb_][tid * 8]);             \
    gload16(V1 + (nk) * 64, &Vs[nb_][2048 + tid * 8]);      \
  } while (0)

  int kt = 0;
  // phase 1a: merged H+L, no diag (kt < qtL); prefetch always valid
  for (; kt < qtL; ++kt) {
    __syncthreads();
    PREFETCH(kt + 1);
    stepHL<false, false, true>(&Ks[kt & 1][0], &Vs[kt & 1][0], Pw,
                               qH0, qH1, qL0, qL1, lH, oH, lL, oL,
                               zero4, ones, c0, c1, col, quad, q_l);
  }
  // phase 1b: kt == qtL: merged, L hits its diagonal (qtL < qtH always)
  {
    __syncthreads();
    PREFETCH(kt + 1);
    stepHL<false, true, true>(&Ks[kt & 1][0], &Vs[kt & 1][0], Pw,
                              qH0, qH1, qL0, qL1, lH, oH, lL, oL,
                              zero4, ones, c0, c1, col, quad, q_l);
    ++kt;
  }
  // phase 2: H only, no diag (empty for adjacent pairing; kept generic)
  for (; kt < qtH; ++kt) {
    __syncthreads();
    PREFETCH(kt + 1);
    stepHL<false, false, false>(&Ks[kt & 1][0], &Vs[kt & 1][0], Pw,
                                qH0, qH1, qL0, qL1, lH, oH, lL, oL,
                                zero4, ones, c0, c1, col, quad, q_l);
  }
  // final: kt == qtH: H diagonal, no prefetch
  {
    __syncthreads();
    stepHL<true, false, false>(&Ks[kt & 1][0], &Vs[kt & 1][0], Pw,
                               qH0, qH1, qL0, qL1, lH, oH, lL, oL,
                               zero4, ones, c0, c1, col, quad, q_l);
  }
#undef PREFETCH

  // epilogue: lacc[0] holds the full l for this lane's q = col.
  const int b = bh >> 4, h = bh & 15;
  {
    const float inv = __builtin_amdgcn_rcpf(lH[0]);
    const size_t base = (size_t)(b * S_LEN + qtH * 64 + q_l) * DM + h * DH;
#pragma unroll
    for (int t = 0; t < 4; ++t) {
      uint2 pk;
      pk.x = pack_bf2(oH[t][0] * inv, oH[t][1] * inv);
      pk.y = pack_bf2(oH[t][2] * inv, oH[t][3] * inv);
      *(uint2*)&AO[base + t * 16 + quad * 4] = pk;
    }
  }
  {
    const float inv = __builtin_amdgcn_rcpf(lL[0]);
    const size_t base = (size_t)(b * S_LEN + qtL * 64 + q_l) * DM + h * DH;
#pragma unroll
    for (int t = 0; t < 4; ++t) {
      uint2 pk;
      pk.x = pack_bf2(oL[t][0] * inv, oL[t][1] * inv);
      pk.y = pack_bf2(oL[t][2] * inv, oL[t][3] * inv);
      *(uint2*)&AO[base + t * 16 + quad * 4] = pk;
    }
  }
}

extern "C" void kernel_launch(void* const* d_in, const int* in_sizes, int n_in,
                              void* d_out, int out_size, void* d_ws, size_t ws_size,
                              hipStream_t stream) {
  const float* X  = (const float*)d_in[0];
  const float* Wq = (const float*)d_in[1];
  const float* Wk = (const float*)d_in[2];
  const float* Wv = (const float*)d_in[3];
  const float* Wo = (const float*)d_in[4];

  u16* Xb   = (u16*)d_ws;            // 8Mi  (reused as AO after QKV)
  u16* Wqkv = Xb + SZX;              // 3Mi  (Wq|Wk|Wv contiguous)
  u16* Wob  = Wqkv + 3 * SZW;        // 1Mi  (contiguous after Wqkv)
  u16* Qb   = Wob + SZW;             // 8Mi  [bh][s][dh], pre-scaled QSCALE
  u16* Kb   = Qb + SZX;              // 8Mi  [bh][s][dh]
  u16* VT   = Kb + SZX;              // 8Mi  [bh][dh][s]
  u16* AO   = Xb;

  cast_all<<<(int)((SZX + 4 * SZW) / 8 / 256), 256, 0, stream>>>(X, Wq, Wk, Wv, Wo, Xb);

  gemm128<0><<<dim3(M_TOK / 128, 3 * DM / 128), 256, 0, stream>>>(Xb, Wqkv, Qb);

  attn_kernel<<<dim3(1024), 256, 0, stream>>>(Qb, Kb, VT, AO);

  gemm128<1><<<dim3(M_TOK / 128, DM / 128), 256, 0, stream>>>(AO, Wob, d_out);
}

// Round 3
// 237.138 us; speedup vs baseline: 1.0751x; 1.0604x over previous
//
#include <hip/hip_runtime.h>

#define S_LEN 2048
#define NH 16
#define DH 64
#define DM 1024
#define M_TOK 8192              // B*S
#define SZX ((size_t)M_TOK * DM)   // 8 Mi elems
#define SZW ((size_t)DM * DM)      // 1 Mi elems (2^20)

typedef unsigned short u16;
typedef unsigned int u32;
typedef __attribute__((ext_vector_type(8))) short bf16x8;   // 8 bf16 = 4 VGPRs
typedef __attribute__((ext_vector_type(4))) float f32x4;

// round-half-up bf16 (error bound == RNE except exact ties)
__device__ __forceinline__ u16 f2bf(float f) {
  union { float f; u32 u; } v; v.f = f;
  return (u16)((v.u + 0x8000u) >> 16);
}
// pack two floats -> (bf16(y)<<16)|bf16(x) in 2 adds + 1 v_perm
__device__ __forceinline__ u32 pack_bf2(float x, float y) {
  union { float f; u32 u; } a, b; a.f = x; b.f = y;
  return __builtin_amdgcn_perm(b.u + 0x8000u, a.u + 0x8000u, 0x07060302u);
}
__device__ __forceinline__ float fast_exp2(float x) {
  float r; asm("v_exp_f32 %0, %1" : "=v"(r) : "v"(x)); return r;
}
// async global->LDS, 16B/lane. dest = wave-uniform base + lane*16.
__device__ __forceinline__ void gload16(const u16* g, u16* l) {
  __builtin_amdgcn_global_load_lds((const __attribute__((address_space(1))) void*)g,
                                   (__attribute__((address_space(3))) void*)l,
                                   16, 0, 0);
}

#define QSCALE 0.18033688f   // 1/sqrt(64) * log2(e)

// Fused cast: X (8Mi) + Wq|Wk|Wv|Wo (4 x 1Mi) -> contiguous bf16 dst.
__global__ __launch_bounds__(256) void cast_all(const float* __restrict__ X,
                                                const float* __restrict__ q,
                                                const float* __restrict__ k,
                                                const float* __restrict__ v,
                                                const float* __restrict__ o,
                                                u16* __restrict__ dst) {
  const int i = (blockIdx.x * 256 + threadIdx.x) * 8;   // [0, 12Mi)
  const float* src;
  int local;
  if (i < (int)SZX) { src = X; local = i; }
  else {
    const int j = i - (int)SZX;
    const int region = j >> 20;
    src = (region == 0) ? q : (region == 1) ? k : (region == 2) ? v : o;
    local = j & ((1 << 20) - 1);
  }
  const float4 a = *(const float4*)(src + local);
  const float4 b = *(const float4*)(src + local + 4);
  uint4 r;
  r.x = pack_bf2(a.x, a.y); r.y = pack_bf2(a.z, a.w);
  r.z = pack_bf2(b.x, b.y); r.w = pack_bf2(b.z, b.w);
  *(uint4*)(dst + i) = r;
}

// ---------------------------------------------------------------------------
// 128x128-tile GEMM, C[m,n] = sum_k A[m,k]*B[n,k], K = 1024, BK = 64.
// 32 KB LDS, 8 global_load_lds + 32 MFMA per barrier pair. XOR swizzle:
// granule (16B) g: row = g>>3, slot = g&7, source kgrp = slot ^ (row&7).
// MODE 0: N=3072 fused QKV epilogue -> Q (scaled QSCALE, [bh][s][dh]),
//         K ([bh][s][dh]), V^T ([bh][dh][s]), bf16. MODE 1: fp32 [M,DM].
// ---------------------------------------------------------------------------
template<int MODE>
__global__ __launch_bounds__(256) void gemm128(const u16* __restrict__ A,
                                               const u16* __restrict__ Bw,
                                               void* __restrict__ Cv) {
  __shared__ __align__(16) u16 As[128 * 64];
  __shared__ __align__(16) u16 Bs[128 * 64];
  const int tid = threadIdx.x;
  const int lane = tid & 63;
  const int wave = tid >> 6;
  const int col = lane & 15, quad = lane >> 4;
  const int wm = (wave & 1) * 64, wn = (wave >> 1) * 64;
  const int m_blk = blockIdx.x * 128, n_blk = blockIdx.y * 128;

  const int srow = tid >> 3;
  const int skg = (tid & 7) ^ (srow & 7);
  const u16* Ag = A + (size_t)(m_blk + srow) * DM + skg * 8;
  const u16* Bg = Bw + (size_t)(n_blk + srow) * DM + skg * 8;

  f32x4 acc[4][4];
#pragma unroll
  for (int i = 0; i < 4; ++i)
#pragma unroll
    for (int j = 0; j < 4; ++j) acc[i][j] = (f32x4){0.f, 0.f, 0.f, 0.f};

  const int c0 = (quad ^ (col & 7)) * 8;   // k-group quad
  const int c1 = c0 ^ 32;                  // k-group quad+4

  for (int k0 = 0; k0 < DM; k0 += 64) {
#pragma unroll
    for (int i = 0; i < 4; ++i) {
      gload16(Ag + (size_t)(32 * i) * DM + k0, &As[tid * 8 + i * 2048]);
      gload16(Bg + (size_t)(32 * i) * DM + k0, &Bs[tid * 8 + i * 2048]);
    }
    __syncthreads();
    bf16x8 af[4], bf[4];
#pragma unroll
    for (int i = 0; i < 4; ++i)
      af[i] = *(const bf16x8*)&As[(wm + i * 16 + col) * 64 + c0];
#pragma unroll
    for (int j = 0; j < 4; ++j)
      bf[j] = *(const bf16x8*)&Bs[(wn + j * 16 + col) * 64 + c0];
#pragma unroll
    for (int i = 0; i < 4; ++i)
#pragma unroll
      for (int j = 0; j < 4; ++j)
        acc[i][j] = __builtin_amdgcn_mfma_f32_16x16x32_bf16(af[i], bf[j], acc[i][j], 0, 0, 0);
#pragma unroll
    for (int i = 0; i < 4; ++i)
      af[i] = *(const bf16x8*)&As[(wm + i * 16 + col) * 64 + c1];
#pragma unroll
    for (int j = 0; j < 4; ++j)
      bf[j] = *(const bf16x8*)&Bs[(wn + j * 16 + col) * 64 + c1];
#pragma unroll
    for (int i = 0; i < 4; ++i)
#pragma unroll
      for (int j = 0; j < 4; ++j)
        acc[i][j] = __builtin_amdgcn_mfma_f32_16x16x32_bf16(af[i], bf[j], acc[i][j], 0, 0, 0);
    __syncthreads();
  }

  // epilogue. C/D: col = lane&15 (n), row = quad*4+reg (m).
#pragma unroll
  for (int i = 0; i < 4; ++i) {
#pragma unroll
    for (int j = 0; j < 4; ++j) {
      const int n = n_blk + wn + j * 16 + col;
      if (MODE == 0) {
        const int which = n >> 10;            // 0=Q 1=K 2=V (uniform per wave)
        const int nn = n & 1023;
        const int h = nn >> 6, dh = nn & 63;
        u16* dst = (u16*)Cv + (size_t)which * SZX;
        const int m0 = m_blk + wm + i * 16 + quad * 4;
        const int b = m0 >> 11;
        if (which == 2) {                     // V^T [bh][dh][s]
          uint2 pk;
          pk.x = pack_bf2(acc[i][j][0], acc[i][j][1]);
          pk.y = pack_bf2(acc[i][j][2], acc[i][j][3]);
          *(uint2*)&dst[((size_t)((b * NH + h) * DH + dh)) * S_LEN + (m0 & 2047)] = pk;
        } else {
          const float sc = (which == 0) ? QSCALE : 1.0f;
#pragma unroll
          for (int r = 0; r < 4; ++r) {
            const int m = m0 + r, s = m & 2047;
            dst[((size_t)(b * NH + h) * S_LEN + s) * DH + dh] = f2bf(acc[i][j][r] * sc);
          }
        }
      } else {
#pragma unroll
        for (int r = 0; r < 4; ++r) {
          const int m = m_blk + wm + i * 16 + quad * 4 + r;
          ((float*)Cv)[(size_t)m * DM + n] = acc[i][j][r];
        }
      }
    }
  }
}

// ---------------------------------------------------------------------------
// Flash attention, causal, S^T form, dbuf K/V, no online max.
// r11: (a) merged step now SHARES V-fragment LDS reads between the H and L
// strips (PV restructured: both P round-trips first, then one V pass feeding
// both oH and oL) -> 28 -> 20 ds_read_b128 per merged step (r2 post-mortem
// showed merged == 2x single cost because V was read per-strip; step cost is
// LDS-traffic-bound: MfmaUtil 18%, VALUBusy 33%). (b) perfect load balance:
// 512 blocks, each runs pairs (15-slot, slot) sequentially = exactly 34
// steps/block (r2's 2..32-step blocks regressed occupancy 16.9->12.9%).
// (c) setprio removed (lockstep 4-wave block = m190's null/negative regime).
// P_H and P_L reuse ONE Pw buffer: DS ops are in-order within a wave
// (read_H retires before write_L) -- same property the r9 kernel relied on.
// Grid: 512, id&7 = XCD, bh = ((id&7)<<3)|(id>>6), slot = (id>>3)&7.
// ---------------------------------------------------------------------------
template<bool DIAG_L>
__device__ __forceinline__ void stepM(const u16* __restrict__ Ksb,
                                      const u16* __restrict__ Vsb,
                                      u16* __restrict__ Pw,
                                      bf16x8 qH0, bf16x8 qH1,
                                      bf16x8 qL0, bf16x8 qL1,
                                      f32x4& lH, f32x4* oH,
                                      f32x4& lL, f32x4* oL,
                                      f32x4 zero4, bf16x8 ones,
                                      int c0, int c1, int col, int quad,
                                      int q_l) {
  const int colc = col & 7;
  f32x4 sH[4], sL[4];
#pragma unroll
  for (int t = 0; t < 4; ++t) {
    const int row = (t * 16 + col) * 64;
    const bf16x8 kf0 = *(const bf16x8*)&Ksb[row + c0];
    const bf16x8 kf1 = *(const bf16x8*)&Ksb[row + c1];
    f32x4 z = __builtin_amdgcn_mfma_f32_16x16x32_bf16(kf0, qH0, zero4, 0, 0, 0);
    sH[t] = __builtin_amdgcn_mfma_f32_16x16x32_bf16(kf1, qH1, z, 0, 0, 0);
    f32x4 y = __builtin_amdgcn_mfma_f32_16x16x32_bf16(kf0, qL0, zero4, 0, 0, 0);
    sL[t] = __builtin_amdgcn_mfma_f32_16x16x32_bf16(kf1, qL1, y, 0, 0, 0);
  }
  // mask + exp (both strips)
#pragma unroll
  for (int t = 0; t < 4; ++t)
#pragma unroll
    for (int r = 0; r < 4; ++r) {
      sH[t][r] = fast_exp2(sH[t][r]);
      if (DIAG_L && (t * 16 + quad * 4 + r) > q_l) sL[t][r] = -1e30f;
      sL[t][r] = fast_exp2(sL[t][r]);
    }
  // ---- P_H round trip ----
#pragma unroll
  for (int t = 0; t < 4; ++t) {
    uint2 pk;
    pk.x = pack_bf2(sH[t][0], sH[t][1]);
    pk.y = pack_bf2(sH[t][2], sH[t][3]);
    const int pg = (((t * 2) + (quad >> 1)) ^ colc) * 8 + (quad & 1) * 4;
    *(uint2*)&Pw[col * 64 + pg] = pk;
  }
  const bf16x8 pfH0 = *(const bf16x8*)&Pw[col * 64 + ((quad ^ colc) * 8)];
  const bf16x8 pfH1 = *(const bf16x8*)&Pw[col * 64 + (((4 + quad) ^ colc) * 8)];
  // ---- P_L round trip (same buffer; in-wave DS order protects H reads) ----
#pragma unroll
  for (int t = 0; t < 4; ++t) {
    uint2 pk;
    pk.x = pack_bf2(sL[t][0], sL[t][1]);
    pk.y = pack_bf2(sL[t][2], sL[t][3]);
    const int pg = (((t * 2) + (quad >> 1)) ^ colc) * 8 + (quad & 1) * 4;
    *(uint2*)&Pw[col * 64 + pg] = pk;
  }
  const bf16x8 pfL0 = *(const bf16x8*)&Pw[col * 64 + ((quad ^ colc) * 8)];
  const bf16x8 pfL1 = *(const bf16x8*)&Pw[col * 64 + (((4 + quad) ^ colc) * 8)];
  // ---- l for both strips ----
  lH = __builtin_amdgcn_mfma_f32_16x16x32_bf16(ones, pfH0, lH, 0, 0, 0);
  lH = __builtin_amdgcn_mfma_f32_16x16x32_bf16(ones, pfH1, lH, 0, 0, 0);
  lL = __builtin_amdgcn_mfma_f32_16x16x32_bf16(ones, pfL0, lL, 0, 0, 0);
  lL = __builtin_amdgcn_mfma_f32_16x16x32_bf16(ones, pfL1, lL, 0, 0, 0);
  // ---- shared-V PV: one V pass feeds both strips ----
#pragma unroll
  for (int t = 0; t < 4; ++t) {
    const int row = (t * 16 + col) * 64;
    const bf16x8 vf0 = *(const bf16x8*)&Vsb[row + c0];
    const bf16x8 vf1 = *(const bf16x8*)&Vsb[row + c1];
    oH[t] = __builtin_amdgcn_mfma_f32_16x16x32_bf16(vf0, pfH0, oH[t], 0, 0, 0);
    oH[t] = __builtin_amdgcn_mfma_f32_16x16x32_bf16(vf1, pfH1, oH[t], 0, 0, 0);
    oL[t] = __builtin_amdgcn_mfma_f32_16x16x32_bf16(vf0, pfL0, oL[t], 0, 0, 0);
    oL[t] = __builtin_amdgcn_mfma_f32_16x16x32_bf16(vf1, pfL1, oL[t], 0, 0, 0);
  }
}

// single-strip (H) step, used only for the H-diagonal tail of each pair.
template<bool DIAG_H>
__device__ __forceinline__ void stepS(const u16* __restrict__ Ksb,
                                      const u16* __restrict__ Vsb,
                                      u16* __restrict__ Pw,
                                      bf16x8 qH0, bf16x8 qH1,
                                      f32x4& lH, f32x4* oH,
                                      f32x4 zero4, bf16x8 ones,
                                      int c0, int c1, int col, int quad,
                                      int q_l) {
  const int colc = col & 7;
  f32x4 sH[4];
#pragma unroll
  for (int t = 0; t < 4; ++t) {
    const int row = (t * 16 + col) * 64;
    const bf16x8 kf0 = *(const bf16x8*)&Ksb[row + c0];
    const bf16x8 kf1 = *(const bf16x8*)&Ksb[row + c1];
    f32x4 z = __builtin_amdgcn_mfma_f32_16x16x32_bf16(kf0, qH0, zero4, 0, 0, 0);
    sH[t] = __builtin_amdgcn_mfma_f32_16x16x32_bf16(kf1, qH1, z, 0, 0, 0);
  }
#pragma unroll
  for (int t = 0; t < 4; ++t)
#pragma unroll
    for (int r = 0; r < 4; ++r) {
      if (DIAG_H && (t * 16 + quad * 4 + r) > q_l) sH[t][r] = -1e30f;
      sH[t][r] = fast_exp2(sH[t][r]);
    }
#pragma unroll
  for (int t = 0; t < 4; ++t) {
    uint2 pk;
    pk.x = pack_bf2(sH[t][0], sH[t][1]);
    pk.y = pack_bf2(sH[t][2], sH[t][3]);
    const int pg = (((t * 2) + (quad >> 1)) ^ colc) * 8 + (quad & 1) * 4;
    *(uint2*)&Pw[col * 64 + pg] = pk;
  }
  const bf16x8 pf0 = *(const bf16x8*)&Pw[col * 64 + ((quad ^ colc) * 8)];
  const bf16x8 pf1 = *(const bf16x8*)&Pw[col * 64 + (((4 + quad) ^ colc) * 8)];
  lH = __builtin_amdgcn_mfma_f32_16x16x32_bf16(ones, pf0, lH, 0, 0, 0);
  lH = __builtin_amdgcn_mfma_f32_16x16x32_bf16(ones, pf1, lH, 0, 0, 0);
#pragma unroll
  for (int t = 0; t < 4; ++t) {
    const int row = (t * 16 + col) * 64;
    const bf16x8 vf0 = *(const bf16x8*)&Vsb[row + c0];
    const bf16x8 vf1 = *(const bf16x8*)&Vsb[row + c1];
    oH[t] = __builtin_amdgcn_mfma_f32_16x16x32_bf16(vf0, pf0, oH[t], 0, 0, 0);
    oH[t] = __builtin_amdgcn_mfma_f32_16x16x32_bf16(vf1, pf1, oH[t], 0, 0, 0);
  }
}

__global__ __launch_bounds__(256) void attn_kernel(const u16* __restrict__ Qg,
                                                   const u16* __restrict__ Kg,
                                                   const u16* __restrict__ Vtg,
                                                   u16* __restrict__ AO) {
  __shared__ __align__(16) u16 Ks[2][64 * 64];     // dbuf, swizzled [kv][dh]
  __shared__ __align__(16) u16 Vs[2][64 * 64];     // dbuf, swizzled [dh][kv]
  __shared__ __align__(16) u16 Ps[4][16 * 64];     // per-wave, XOR-swizzled

  const int id = blockIdx.x;                    // 0..511
  const int bh = ((id & 7) << 3) | (id >> 6);   // 0..63 (id&7 = XCD colocate)
  const int slot = (id >> 3) & 7;               // 0..7
  const int tid = threadIdx.x, lane = tid & 63, wave = tid >> 6;
  const int col = lane & 15, quad = lane >> 4;

  const u16* Qb = Qg + (size_t)bh * S_LEN * DH;
  const u16* Kb = Kg + (size_t)bh * S_LEN * DH;
  const u16* Vb = Vtg + (size_t)bh * DH * S_LEN;

  const f32x4 zero4 = (f32x4){0.f, 0.f, 0.f, 0.f};
  const bf16x8 ones = (bf16x8){0x3F80, 0x3F80, 0x3F80, 0x3F80,
                               0x3F80, 0x3F80, 0x3F80, 0x3F80};   // bf16 1.0

  // staging granules: row = g>>3, slot = g&7, source grp = slot^(row&7).
  const int sr0 = tid >> 3;
  const int sk0 = (tid & 7) ^ (sr0 & 7);
  const u16* K0 = Kb + (size_t)sr0 * DH + sk0 * 8;
  const u16* K1 = Kb + (size_t)(sr0 + 32) * DH + sk0 * 8;
  const u16* V0 = Vb + (size_t)sr0 * S_LEN + sk0 * 8;
  const u16* V1 = Vb + (size_t)(sr0 + 32) * S_LEN + sk0 * 8;

  const int c0 = (quad ^ (col & 7)) * 8;
  const int c1 = c0 ^ 32;
  const int q_l = wave * 16 + col;
  u16* Pw = &Ps[wave][0];
  const int b = bh >> 4, h = bh & 15;

#define PREFETCH(nk) do {                                   \
    const int nb_ = (nk) & 1;                               \
    gload16(K0 + (size_t)(nk) * 64 * DH, &Ks[nb_][tid * 8]);\
    gload16(K1 + (size_t)(nk) * 64 * DH, &Ks[nb_][2048 + tid * 8]); \
    gload16(V0 + (nk) * 64, &Vs[nb_][tid * 8]);             \
    gload16(V1 + (nk) * 64, &Vs[nb_][2048 + tid * 8]);      \
  } while (0)

  for (int pi = 0; pi < 2; ++pi) {
    const int p = pi ? slot : (15 - slot);      // long pair first
    const int qtH = 2 * p + 1, qtL = 2 * p;

    // Q B-frags: n = q = col, k = dh = quad*8+j (+32); qtL row = qtH row - 64
    const u16* qrowH = Qb + (size_t)(qtH * 64 + wave * 16 + col) * DH + quad * 8;
    const bf16x8 qH0 = *(const bf16x8*)(qrowH);
    const bf16x8 qH1 = *(const bf16x8*)(qrowH + 32);
    const bf16x8 qL0 = *(const bf16x8*)(qrowH - 64 * DH);
    const bf16x8 qL1 = *(const bf16x8*)(qrowH - 64 * DH + 32);

    f32x4 lH = zero4, lL = zero4;
    f32x4 oH[4], oL[4];
#pragma unroll
    for (int t = 0; t < 4; ++t) { oH[t] = zero4; oL[t] = zero4; }

    // restage guard (pair B: prior pair's last reads must finish first)
    __syncthreads();
    // prologue: stage tile 0 into buffer 0
    gload16(K0, &Ks[0][tid * 8]);
    gload16(K1, &Ks[0][2048 + tid * 8]);
    gload16(V0, &Vs[0][tid * 8]);
    gload16(V1, &Vs[0][2048 + tid * 8]);

    int kt = 0;
    // merged H+L, no diag (kt < qtL)
    for (; kt < qtL; ++kt) {
      __syncthreads();
      PREFETCH(kt + 1);
      stepM<false>(&Ks[kt & 1][0], &Vs[kt & 1][0], Pw,
                   qH0, qH1, qL0, qL1, lH, oH, lL, oL,
                   zero4, ones, c0, c1, col, quad, q_l);
    }
    // kt == qtL: merged, L hits its diagonal
    {
      __syncthreads();
      PREFETCH(kt + 1);
      stepM<true>(&Ks[kt & 1][0], &Vs[kt & 1][0], Pw,
                  qH0, qH1, qL0, qL1, lH, oH, lL, oL,
                  zero4, ones, c0, c1, col, quad, q_l);
      ++kt;
    }
    // kt == qtH: single H, diagonal, no prefetch
    {
      __syncthreads();
      stepS<true>(&Ks[kt & 1][0], &Vs[kt & 1][0], Pw,
                  qH0, qH1, lH, oH, zero4, ones, c0, c1, col, quad, q_l);
    }

    // epilogue: l[0] holds the full l for this lane's q = col.
    {
      const float inv = __builtin_amdgcn_rcpf(lH[0]);
      const size_t base = (size_t)(b * S_LEN + qtH * 64 + q_l) * DM + h * DH;
#pragma unroll
      for (int t = 0; t < 4; ++t) {
        uint2 pk;
        pk.x = pack_bf2(oH[t][0] * inv, oH[t][1] * inv);
        pk.y = pack_bf2(oH[t][2] * inv, oH[t][3] * inv);
        *(uint2*)&AO[base + t * 16 + quad * 4] = pk;
      }
    }
    {
      const float inv = __builtin_amdgcn_rcpf(lL[0]);
      const size_t base = (size_t)(b * S_LEN + qtL * 64 + q_l) * DM + h * DH;
#pragma unroll
      for (int t = 0; t < 4; ++t) {
        uint2 pk;
        pk.x = pack_bf2(oL[t][0] * inv, oL[t][1] * inv);
        pk.y = pack_bf2(oL[t][2] * inv, oL[t][3] * inv);
        *(uint2*)&AO[base + t * 16 + quad * 4] = pk;
      }
    }
  }
#undef PREFETCH
}

extern "C" void kernel_launch(void* const* d_in, const int* in_sizes, int n_in,
                              void* d_out, int out_size, void* d_ws, size_t ws_size,
                              hipStream_t stream) {
  const float* X  = (const float*)d_in[0];
  const float* Wq = (const float*)d_in[1];
  const float* Wk = (const float*)d_in[2];
  const float* Wv = (const float*)d_in[3];
  const float* Wo = (const float*)d_in[4];

  u16* Xb   = (u16*)d_ws;            // 8Mi  (reused as AO after QKV)
  u16* Wqkv = Xb + SZX;              // 3Mi  (Wq|Wk|Wv contiguous)
  u16* Wob  = Wqkv + 3 * SZW;        // 1Mi  (contiguous after Wqkv)
  u16* Qb   = Wob + SZW;             // 8Mi  [bh][s][dh], pre-scaled QSCALE
  u16* Kb   = Qb + SZX;              // 8Mi  [bh][s][dh]
  u16* VT   = Kb + SZX;              // 8Mi  [bh][dh][s]
  u16* AO   = Xb;

  cast_all<<<(int)((SZX + 4 * SZW) / 8 / 256), 256, 0, stream>>>(X, Wq, Wk, Wv, Wo, Xb);

  gemm128<0><<<dim3(M_TOK / 128, 3 * DM / 128), 256, 0, stream>>>(Xb, Wqkv, Qb);

  attn_kernel<<<dim3(512), 256, 0, stream>>>(Qb, Kb, VT, AO);

  gemm128<1><<<dim3(M_TOK / 128, DM / 128), 256, 0, stream>>>(AO, Wob, d_out);
}

// Round 6
// 227.415 us; speedup vs baseline: 1.1211x; 1.0428x over previous
//
#include <hip/hip_runtime.h>

#define S_LEN 2048
#define NH 16
#define DH 64
#define DM 1024
#define M_TOK 8192              // B*S
#define SZX ((size_t)M_TOK * DM)   // 8 Mi elems
#define SZW ((size_t)DM * DM)      // 1 Mi elems (2^20)

typedef unsigned short u16;
typedef unsigned int u32;
typedef __attribute__((ext_vector_type(8))) short bf16x8;   // 8 bf16 = 4 VGPRs
typedef __attribute__((ext_vector_type(4))) float f32x4;

// round-half-up bf16 (error bound == RNE except exact ties)
__device__ __forceinline__ u16 f2bf(float f) {
  union { float f; u32 u; } v; v.f = f;
  return (u16)((v.u + 0x8000u) >> 16);
}
// pack two floats -> (bf16(y)<<16)|bf16(x) in 2 adds + 1 v_perm
__device__ __forceinline__ u32 pack_bf2(float x, float y) {
  union { float f; u32 u; } a, b; a.f = x; b.f = y;
  return __builtin_amdgcn_perm(b.u + 0x8000u, a.u + 0x8000u, 0x07060302u);
}
__device__ __forceinline__ float fast_exp2(float x) {
  float r; asm("v_exp_f32 %0, %1" : "=v"(r) : "v"(x)); return r;
}
// async global->LDS, 16B/lane. dest = wave-uniform base + lane*16.
__device__ __forceinline__ void gload16(const u16* g, u16* l) {
  __builtin_amdgcn_global_load_lds((const __attribute__((address_space(1))) void*)g,
                                   (__attribute__((address_space(3))) void*)l,
                                   16, 0, 0);
}

#define QSCALE 0.18033688f   // 1/sqrt(64) * log2(e)

// Fused cast: X (8Mi) + Wq|Wk|Wv|Wo (4 x 1Mi) -> contiguous bf16 dst.
__global__ __launch_bounds__(256) void cast_all(const float* __restrict__ X,
                                                const float* __restrict__ q,
                                                const float* __restrict__ k,
                                                const float* __restrict__ v,
                                                const float* __restrict__ o,
                                                u16* __restrict__ dst) {
  const int i = (blockIdx.x * 256 + threadIdx.x) * 8;   // [0, 12Mi)
  const float* src;
  int local;
  if (i < (int)SZX) { src = X; local = i; }
  else {
    const int j = i - (int)SZX;
    const int region = j >> 20;
    src = (region == 0) ? q : (region == 1) ? k : (region == 2) ? v : o;
    local = j & ((1 << 20) - 1);
  }
  const float4 a = *(const float4*)(src + local);
  const float4 b = *(const float4*)(src + local + 4);
  uint4 r;
  r.x = pack_bf2(a.x, a.y); r.y = pack_bf2(a.z, a.w);
  r.z = pack_bf2(b.x, b.y); r.w = pack_bf2(b.z, b.w);
  *(uint4*)(dst + i) = r;
}

// ---------------------------------------------------------------------------
// 128x128-tile GEMM, C[m,n] = sum_k A[m,k]*B[n,k], K = 1024, BK = 64.
// 32 KB LDS, 8 global_load_lds + 32 MFMA per barrier pair. XOR swizzle:
// granule (16B) g: row = g>>3, slot = g&7, source kgrp = slot ^ (row&7).
// MODE 0: N=3072 fused QKV epilogue -> Q (scaled QSCALE, [bh][s][dh]),
//         K ([bh][s][dh]), V^T ([bh][dh][s]), bf16. MODE 1: fp32 [M,DM].
// ---------------------------------------------------------------------------
template<int MODE>
__global__ __launch_bounds__(256) void gemm128(const u16* __restrict__ A,
                                               const u16* __restrict__ Bw,
                                               void* __restrict__ Cv) {
  __shared__ __align__(16) u16 As[128 * 64];
  __shared__ __align__(16) u16 Bs[128 * 64];
  const int tid = threadIdx.x;
  const int lane = tid & 63;
  const int wave = tid >> 6;
  const int col = lane & 15, quad = lane >> 4;
  const int wm = (wave & 1) * 64, wn = (wave >> 1) * 64;
  const int m_blk = blockIdx.x * 128, n_blk = blockIdx.y * 128;

  const int srow = tid >> 3;
  const int skg = (tid & 7) ^ (srow & 7);
  const u16* Ag = A + (size_t)(m_blk + srow) * DM + skg * 8;
  const u16* Bg = Bw + (size_t)(n_blk + srow) * DM + skg * 8;

  f32x4 acc[4][4];
#pragma unroll
  for (int i = 0; i < 4; ++i)
#pragma unroll
    for (int j = 0; j < 4; ++j) acc[i][j] = (f32x4){0.f, 0.f, 0.f, 0.f};

  const int c0 = (quad ^ (col & 7)) * 8;   // k-group quad
  const int c1 = c0 ^ 32;                  // k-group quad+4

  for (int k0 = 0; k0 < DM; k0 += 64) {
#pragma unroll
    for (int i = 0; i < 4; ++i) {
      gload16(Ag + (size_t)(32 * i) * DM + k0, &As[tid * 8 + i * 2048]);
      gload16(Bg + (size_t)(32 * i) * DM + k0, &Bs[tid * 8 + i * 2048]);
    }
    __syncthreads();
    bf16x8 af[4], bf[4];
#pragma unroll
    for (int i = 0; i < 4; ++i)
      af[i] = *(const bf16x8*)&As[(wm + i * 16 + col) * 64 + c0];
#pragma unroll
    for (int j = 0; j < 4; ++j)
      bf[j] = *(const bf16x8*)&Bs[(wn + j * 16 + col) * 64 + c0];
#pragma unroll
    for (int i = 0; i < 4; ++i)
#pragma unroll
      for (int j = 0; j < 4; ++j)
        acc[i][j] = __builtin_amdgcn_mfma_f32_16x16x32_bf16(af[i], bf[j], acc[i][j], 0, 0, 0);
#pragma unroll
    for (int i = 0; i < 4; ++i)
      af[i] = *(const bf16x8*)&As[(wm + i * 16 + col) * 64 + c1];
#pragma unroll
    for (int j = 0; j < 4; ++j)
      bf[j] = *(const bf16x8*)&Bs[(wn + j * 16 + col) * 64 + c1];
#pragma unroll
    for (int i = 0; i < 4; ++i)
#pragma unroll
      for (int j = 0; j < 4; ++j)
        acc[i][j] = __builtin_amdgcn_mfma_f32_16x16x32_bf16(af[i], bf[j], acc[i][j], 0, 0, 0);
    __syncthreads();
  }

  // epilogue. C/D: col = lane&15 (n), row = quad*4+reg (m).
#pragma unroll
  for (int i = 0; i < 4; ++i) {
#pragma unroll
    for (int j = 0; j < 4; ++j) {
      const int n = n_blk + wn + j * 16 + col;
      if (MODE == 0) {
        const int which = n >> 10;            // 0=Q 1=K 2=V (uniform per wave)
        const int nn = n & 1023;
        const int h = nn >> 6, dh = nn & 63;
        u16* dst = (u16*)Cv + (size_t)which * SZX;
        const int m0 = m_blk + wm + i * 16 + quad * 4;
        const int b = m0 >> 11;
        if (which == 2) {                     // V^T [bh][dh][s]
          uint2 pk;
          pk.x = pack_bf2(acc[i][j][0], acc[i][j][1]);
          pk.y = pack_bf2(acc[i][j][2], acc[i][j][3]);
          *(uint2*)&dst[((size_t)((b * NH + h) * DH + dh)) * S_LEN + (m0 & 2047)] = pk;
        } else {
          const float sc = (which == 0) ? QSCALE : 1.0f;
#pragma unroll
          for (int r = 0; r < 4; ++r) {
            const int m = m0 + r, s = m & 2047;
            dst[((size_t)(b * NH + h) * S_LEN + s) * DH + dh] = f2bf(acc[i][j][r] * sc);
          }
        }
      } else {
#pragma unroll
        for (int r = 0; r < 4; ++r) {
          const int m = m_blk + wm + i * 16 + quad * 4 + r;
          ((float*)Cv)[(size_t)m * DM + n] = acc[i][j][r];
        }
      }
    }
  }
}

// ---------------------------------------------------------------------------
// Flash attention, causal, S^T form, dbuf K/V, no online max.
// r14 = r3 (verified-good: adjacent pairing, shared-V merged step, balanced
// 512x34-step blocks) with the barrier window WIDENED to 2 kv-tiles:
// stage 128 kv rows (8 gload16) per window, then run the VERBATIM r3
// stepM/stepS twice (tile 2w, tile 2w+1) with no barrier between. Causality
// maps exactly: pair (qtH=2p+1, qtL=2p) = p full windows {stepM<false> x2}
// + final window {stepM<true>(tile 2p, L-diag), stepS<true>(tile 2p+1,
// H-diag)}. Sync points per bh: 288 -> 152 (r3 counters: MfmaUtil 22%,
// FETCH=compulsory -> residual is the per-barrier vmcnt(0) drain tax).
// All numeric / P-round-trip / swizzle code is byte-identical to r3.
// (r12/r13's 4-strip rewrite failed verification twice with an
// unlocalizable ~one-tile-mass error; abandoned per rigor discipline.)
// ---------------------------------------------------------------------------
template<bool DIAG_L>
__device__ __forceinline__ void stepM(const u16* __restrict__ Ksb,
                                      const u16* __restrict__ Vsb,
                                      u16* __restrict__ Pw,
                                      bf16x8 qH0, bf16x8 qH1,
                                      bf16x8 qL0, bf16x8 qL1,
                                      f32x4& lH, f32x4* oH,
                                      f32x4& lL, f32x4* oL,
                                      f32x4 zero4, bf16x8 ones,
                                      int c0, int c1, int col, int quad,
                                      int q_l) {
  const int colc = col & 7;
  f32x4 sH[4], sL[4];
#pragma unroll
  for (int t = 0; t < 4; ++t) {
    const int row = (t * 16 + col) * 64;
    const bf16x8 kf0 = *(const bf16x8*)&Ksb[row + c0];
    const bf16x8 kf1 = *(const bf16x8*)&Ksb[row + c1];
    f32x4 z = __builtin_amdgcn_mfma_f32_16x16x32_bf16(kf0, qH0, zero4, 0, 0, 0);
    sH[t] = __builtin_amdgcn_mfma_f32_16x16x32_bf16(kf1, qH1, z, 0, 0, 0);
    f32x4 y = __builtin_amdgcn_mfma_f32_16x16x32_bf16(kf0, qL0, zero4, 0, 0, 0);
    sL[t] = __builtin_amdgcn_mfma_f32_16x16x32_bf16(kf1, qL1, y, 0, 0, 0);
  }
  // mask + exp (both strips)
#pragma unroll
  for (int t = 0; t < 4; ++t)
#pragma unroll
    for (int r = 0; r < 4; ++r) {
      sH[t][r] = fast_exp2(sH[t][r]);
      if (DIAG_L && (t * 16 + quad * 4 + r) > q_l) sL[t][r] = -1e30f;
      sL[t][r] = fast_exp2(sL[t][r]);
    }
  // ---- P_H round trip ----
#pragma unroll
  for (int t = 0; t < 4; ++t) {
    uint2 pk;
    pk.x = pack_bf2(sH[t][0], sH[t][1]);
    pk.y = pack_bf2(sH[t][2], sH[t][3]);
    const int pg = (((t * 2) + (quad >> 1)) ^ colc) * 8 + (quad & 1) * 4;
    *(uint2*)&Pw[col * 64 + pg] = pk;
  }
  const bf16x8 pfH0 = *(const bf16x8*)&Pw[col * 64 + ((quad ^ colc) * 8)];
  const bf16x8 pfH1 = *(const bf16x8*)&Pw[col * 64 + (((4 + quad) ^ colc) * 8)];
  // ---- P_L round trip (same buffer; in-wave DS order protects H reads) ----
#pragma unroll
  for (int t = 0; t < 4; ++t) {
    uint2 pk;
    pk.x = pack_bf2(sL[t][0], sL[t][1]);
    pk.y = pack_bf2(sL[t][2], sL[t][3]);
    const int pg = (((t * 2) + (quad >> 1)) ^ colc) * 8 + (quad & 1) * 4;
    *(uint2*)&Pw[col * 64 + pg] = pk;
  }
  const bf16x8 pfL0 = *(const bf16x8*)&Pw[col * 64 + ((quad ^ colc) * 8)];
  const bf16x8 pfL1 = *(const bf16x8*)&Pw[col * 64 + (((4 + quad) ^ colc) * 8)];
  // ---- l for both strips ----
  lH = __builtin_amdgcn_mfma_f32_16x16x32_bf16(ones, pfH0, lH, 0, 0, 0);
  lH = __builtin_amdgcn_mfma_f32_16x16x32_bf16(ones, pfH1, lH, 0, 0, 0);
  lL = __builtin_amdgcn_mfma_f32_16x16x32_bf16(ones, pfL0, lL, 0, 0, 0);
  lL = __builtin_amdgcn_mfma_f32_16x16x32_bf16(ones, pfL1, lL, 0, 0, 0);
  // ---- shared-V PV: one V pass feeds both strips ----
#pragma unroll
  for (int t = 0; t < 4; ++t) {
    const int row = (t * 16 + col) * 64;
    const bf16x8 vf0 = *(const bf16x8*)&Vsb[row + c0];
    const bf16x8 vf1 = *(const bf16x8*)&Vsb[row + c1];
    oH[t] = __builtin_amdgcn_mfma_f32_16x16x32_bf16(vf0, pfH0, oH[t], 0, 0, 0);
    oH[t] = __builtin_amdgcn_mfma_f32_16x16x32_bf16(vf1, pfH1, oH[t], 0, 0, 0);
    oL[t] = __builtin_amdgcn_mfma_f32_16x16x32_bf16(vf0, pfL0, oL[t], 0, 0, 0);
    oL[t] = __builtin_amdgcn_mfma_f32_16x16x32_bf16(vf1, pfL1, oL[t], 0, 0, 0);
  }
}

// single-strip (H) step, used only for the H-diagonal tail of each pair.
template<bool DIAG_H>
__device__ __forceinline__ void stepS(const u16* __restrict__ Ksb,
                                      const u16* __restrict__ Vsb,
                                      u16* __restrict__ Pw,
                                      bf16x8 qH0, bf16x8 qH1,
                                      f32x4& lH, f32x4* oH,
                                      f32x4 zero4, bf16x8 ones,
                                      int c0, int c1, int col, int quad,
                                      int q_l) {
  const int colc = col & 7;
  f32x4 sH[4];
#pragma unroll
  for (int t = 0; t < 4; ++t) {
    const int row = (t * 16 + col) * 64;
    const bf16x8 kf0 = *(const bf16x8*)&Ksb[row + c0];
    const bf16x8 kf1 = *(const bf16x8*)&Ksb[row + c1];
    f32x4 z = __builtin_amdgcn_mfma_f32_16x16x32_bf16(kf0, qH0, zero4, 0, 0, 0);
    sH[t] = __builtin_amdgcn_mfma_f32_16x16x32_bf16(kf1, qH1, z, 0, 0, 0);
  }
#pragma unroll
  for (int t = 0; t < 4; ++t)
#pragma unroll
    for (int r = 0; r < 4; ++r) {
      if (DIAG_H && (t * 16 + quad * 4 + r) > q_l) sH[t][r] = -1e30f;
      sH[t][r] = fast_exp2(sH[t][r]);
    }
#pragma unroll
  for (int t = 0; t < 4; ++t) {
    uint2 pk;
    pk.x = pack_bf2(sH[t][0], sH[t][1]);
    pk.y = pack_bf2(sH[t][2], sH[t][3]);
    const int pg = (((t * 2) + (quad >> 1)) ^ colc) * 8 + (quad & 1) * 4;
    *(uint2*)&Pw[col * 64 + pg] = pk;
  }
  const bf16x8 pf0 = *(const bf16x8*)&Pw[col * 64 + ((quad ^ colc) * 8)];
  const bf16x8 pf1 = *(const bf16x8*)&Pw[col * 64 + (((4 + quad) ^ colc) * 8)];
  lH = __builtin_amdgcn_mfma_f32_16x16x32_bf16(ones, pf0, lH, 0, 0, 0);
  lH = __builtin_amdgcn_mfma_f32_16x16x32_bf16(ones, pf1, lH, 0, 0, 0);
#pragma unroll
  for (int t = 0; t < 4; ++t) {
    const int row = (t * 16 + col) * 64;
    const bf16x8 vf0 = *(const bf16x8*)&Vsb[row + c0];
    const bf16x8 vf1 = *(const bf16x8*)&Vsb[row + c1];
    oH[t] = __builtin_amdgcn_mfma_f32_16x16x32_bf16(vf0, pf0, oH[t], 0, 0, 0);
    oH[t] = __builtin_amdgcn_mfma_f32_16x16x32_bf16(vf1, pf1, oH[t], 0, 0, 0);
  }
}

__global__ __launch_bounds__(256) void attn_kernel(const u16* __restrict__ Qg,
                                                   const u16* __restrict__ Kg,
                                                   const u16* __restrict__ Vtg,
                                                   u16* __restrict__ AO) {
  __shared__ __align__(16) u16 Ks[2][2][64 * 64];  // dbuf x 2 tiles, swizzled
  __shared__ __align__(16) u16 Vs[2][2][64 * 64];  // dbuf x 2 tiles, swizzled
  __shared__ __align__(16) u16 Ps[4][16 * 64];     // per-wave, XOR-swizzled

  const int id = blockIdx.x;                    // 0..511
  const int bh = ((id & 7) << 3) | (id >> 6);   // 0..63 (id&7 = XCD colocate)
  const int slot = (id >> 3) & 7;               // 0..7
  const int tid = threadIdx.x, lane = tid & 63, wave = tid >> 6;
  const int col = lane & 15, quad = lane >> 4;

  const u16* Qb = Qg + (size_t)bh * S_LEN * DH;
  const u16* Kb = Kg + (size_t)bh * S_LEN * DH;
  const u16* Vb = Vtg + (size_t)bh * DH * S_LEN;

  const f32x4 zero4 = (f32x4){0.f, 0.f, 0.f, 0.f};
  const bf16x8 ones = (bf16x8){0x3F80, 0x3F80, 0x3F80, 0x3F80,
                               0x3F80, 0x3F80, 0x3F80, 0x3F80};   // bf16 1.0

  // staging granules: row = g>>3, slot = g&7, source grp = slot^(row&7).
  const int sr0 = tid >> 3;
  const int sk0 = (tid & 7) ^ (sr0 & 7);
  const u16* K0 = Kb + (size_t)sr0 * DH + sk0 * 8;
  const u16* K1 = Kb + (size_t)(sr0 + 32) * DH + sk0 * 8;
  const u16* V0 = Vb + (size_t)sr0 * S_LEN + sk0 * 8;
  const u16* V1 = Vb + (size_t)(sr0 + 32) * S_LEN + sk0 * 8;

  const int c0 = (quad ^ (col & 7)) * 8;
  const int c1 = c0 ^ 32;
  const int q_l = wave * 16 + col;
  u16* Pw = &Ps[wave][0];
  const int b = bh >> 4, h = bh & 15;

  // window w covers kv tiles 2w and 2w+1 (128 rows), staged into dbuf nb.
#define STAGEW(w, nb) do {                                            \
    gload16(K0 + (size_t)(2 * (w)) * 64 * DH,     &Ks[nb][0][tid * 8]);        \
    gload16(K1 + (size_t)(2 * (w)) * 64 * DH,     &Ks[nb][0][2048 + tid * 8]); \
    gload16(K0 + (size_t)(2 * (w) + 1) * 64 * DH, &Ks[nb][1][tid * 8]);        \
    gload16(K1 + (size_t)(2 * (w) + 1) * 64 * DH, &Ks[nb][1][2048 + tid * 8]); \
    gload16(V0 + (2 * (w)) * 64,                  &Vs[nb][0][tid * 8]);        \
    gload16(V1 + (2 * (w)) * 64,                  &Vs[nb][0][2048 + tid * 8]); \
    gload16(V0 + (2 * (w) + 1) * 64,              &Vs[nb][1][tid * 8]);        \
    gload16(V1 + (2 * (w) + 1) * 64,              &Vs[nb][1][2048 + tid * 8]); \
  } while (0)

  for (int pi = 0; pi < 2; ++pi) {
    const int p = pi ? slot : (15 - slot);      // long pair first
    const int qtH = 2 * p + 1;

    // Q B-frags: n = q = col, k = dh = quad*8+j (+32); qtL row = qtH row - 64
    const u16* qrowH = Qb + (size_t)(qtH * 64 + wave * 16 + col) * DH + quad * 8;
    const bf16x8 qH0 = *(const bf16x8*)(qrowH);
    const bf16x8 qH1 = *(const bf16x8*)(qrowH + 32);
    const bf16x8 qL0 = *(const bf16x8*)(qrowH - 64 * DH);
    const bf16x8 qL1 = *(const bf16x8*)(qrowH - 64 * DH + 32);

    f32x4 lH = zero4, lL = zero4;
    f32x4 oH[4], oL[4];
#pragma unroll
    for (int t = 0; t < 4; ++t) { oH[t] = zero4; oL[t] = zero4; }

    // restage guard (pair B: prior pair's last reads must retire first)
    __syncthreads();
    STAGEW(0, 0);

    // full windows w = 0..p-1 (tiles 2w, 2w+1 fully visible to both strips)
    for (int w = 0; w < p; ++w) {
      __syncthreads();
      STAGEW(w + 1, (w + 1) & 1);
      stepM<false>(&Ks[w & 1][0][0], &Vs[w & 1][0][0], Pw,
                   qH0, qH1, qL0, qL1, lH, oH, lL, oL,
                   zero4, ones, c0, c1, col, quad, q_l);
      stepM<false>(&Ks[w & 1][1][0], &Vs[w & 1][1][0], Pw,
                   qH0, qH1, qL0, qL1, lH, oH, lL, oL,
                   zero4, ones, c0, c1, col, quad, q_l);
    }
    // final window w == p: tile 2p = L-diagonal (merged), tile 2p+1 =
    // H-diagonal (single strip; L's extent ended at 2p).
    {
      __syncthreads();
      stepM<true>(&Ks[p & 1][0][0], &Vs[p & 1][0][0], Pw,
                  qH0, qH1, qL0, qL1, lH, oH, lL, oL,
                  zero4, ones, c0, c1, col, quad, q_l);
      stepS<true>(&Ks[p & 1][1][0], &Vs[p & 1][1][0], Pw,
                  qH0, qH1, lH, oH, zero4, ones, c0, c1, col, quad, q_l);
    }

    // epilogue: l[0] holds the full l for this lane's q = q_l.
    {
      const float inv = __builtin_amdgcn_rcpf(lH[0]);
      const size_t base = (size_t)(b * S_LEN + qtH * 64 + q_l) * DM + h * DH;
#pragma unroll
      for (int t = 0; t < 4; ++t) {
        uint2 pk;
        pk.x = pack_bf2(oH[t][0] * inv, oH[t][1] * inv);
        pk.y = pack_bf2(oH[t][2] * inv, oH[t][3] * inv);
        *(uint2*)&AO[base + t * 16 + quad * 4] = pk;
      }
    }
    {
      const float inv = __builtin_amdgcn_rcpf(lL[0]);
      const size_t base = (size_t)(b * S_LEN + (qtH - 1) * 64 + q_l) * DM + h * DH;
#pragma unroll
      for (int t = 0; t < 4; ++t) {
        uint2 pk;
        pk.x = pack_bf2(oL[t][0] * inv, oL[t][1] * inv);
        pk.y = pack_bf2(oL[t][2] * inv, oL[t][3] * inv);
        *(uint2*)&AO[base + t * 16 + quad * 4] = pk;
      }
    }
  }
#undef STAGEW
}

extern "C" void kernel_launch(void* const* d_in, const int* in_sizes, int n_in,
                              void* d_out, int out_size, void* d_ws, size_t ws_size,
                              hipStream_t stream) {
  const float* X  = (const float*)d_in[0];
  const float* Wq = (const float*)d_in[1];
  const float* Wk = (const float*)d_in[2];
  const float* Wv = (const float*)d_in[3];
  const float* Wo = (const float*)d_in[4];

  u16* Xb   = (u16*)d_ws;            // 8Mi  (reused as AO after QKV)
  u16* Wqkv = Xb + SZX;              // 3Mi  (Wq|Wk|Wv contiguous)
  u16* Wob  = Wqkv + 3 * SZW;        // 1Mi  (contiguous after Wqkv)
  u16* Qb   = Wob + SZW;             // 8Mi  [bh][s][dh], pre-scaled QSCALE
  u16* Kb   = Qb + SZX;              // 8Mi  [bh][s][dh]
  u16* VT   = Kb + SZX;              // 8Mi  [bh][dh][s]
  u16* AO   = Xb;

  cast_all<<<(int)((SZX + 4 * SZW) / 8 / 256), 256, 0, stream>>>(X, Wq, Wk, Wv, Wo, Xb);

  gemm128<0><<<dim3(M_TOK / 128, 3 * DM / 128), 256, 0, stream>>>(Xb, Wqkv, Qb);

  attn_kernel<<<dim3(512), 256, 0, stream>>>(Qb, Kb, VT, AO);

  gemm128<1><<<dim3(M_TOK / 128, DM / 128), 256, 0, stream>>>(AO, Wob, d_out);
}